// Round 16
// baseline (769.110 us; speedup 1.0000x reference)
//
#include <hip/hip_runtime.h>

#define N_NODES 100000
#define N_EDGES 1600000
#define N_GRAPHS 64
#define DIM 128
#define BN_EPS 1e-5f
#define EPAD 2000000          // sentinel-filled esrc capacity (needs 1,903,419)

#define NB_DEG 6250           // dego atomics: 6250*256 = 1.6M edges
#define NB_EMB 6250           // embed: 100k nodes * 16 thr
#define NB_SENT 977           // esrc sentinel fill, 8 per thread
#define NB_WPREP 192          // 3*128*128/256
#define NB_HIST 391           // coarse hist: 391 chunks * 4096 edges
#define NBUCK 782             // coarse buckets = dst>>7 (100000/128)
#define NG (NBUCK * NB_HIST)  // count-matrix size = 305762
#define NB_SCANG 1195         // ceil(NG/256)
#define BUCK_RESERVE 388      // cnt + 128*3 pad + 4 align slack

#define AT_STRIDE 136  // 128 + 8 pad: 2-way-only LDS bank aliasing

typedef unsigned short ushort_t;
typedef unsigned char uchar_t;
typedef unsigned int uint_t;
typedef __attribute__((ext_vector_type(8))) short bf16x8;
typedef __attribute__((ext_vector_type(4))) float f32x4;

__device__ __forceinline__ float bfl(uint_t u) {
    union { uint_t i; float f; } v; v.i = u << 16; return v.f;
}
__device__ __forceinline__ float bfh(uint_t u) {
    union { uint_t i; float f; } v; v.i = u & 0xffff0000u; return v.f;
}
__device__ __forceinline__ ushort_t f2bf(float f) {
    union { float f; uint_t i; } v; v.f = f;
    uint_t x = v.i;
    return (ushort_t)((x + 0x7fffu + ((x >> 16) & 1u)) >> 16);
}
__device__ __forceinline__ uint_t pack2(float lo, float hi) {
    return ((uint_t)f2bf(hi) << 16) | (uint_t)f2bf(lo);
}

// ---------------- zero scratch ----------------
__global__ void k_zero(int* __restrict__ p, int n) {
    int i = blockIdx.x * blockDim.x + threadIdx.x;
    if (i < n) p[i] = 0;
}

// ---------------- front mega-kernel: {dego | embed | sentinel | wprep | coarse-hist} ----------------
__global__ void k_front(const int* __restrict__ src, const int* __restrict__ dst,
                        int* __restrict__ dego,
                        const int* __restrict__ tokens, const float* __restrict__ embed,
                        ushort_t* __restrict__ bufH, ushort_t* __restrict__ bufA,
                        int* __restrict__ esrc,
                        const float* __restrict__ w1, const float* __restrict__ w2,
                        const float* __restrict__ w3, ushort_t* __restrict__ wbt,
                        int* __restrict__ G) {
    __shared__ int hh[NBUCK];
    int b = blockIdx.x;
    int t = threadIdx.x;
    if (b < NB_DEG) {
        int e = b * 256 + t;
        if (e < N_EDGES) atomicAdd(&dego[src[e]], 1);
        return;
    }
    b -= NB_DEG;
    if (b < NB_EMB) {  // raw embedding gather (ns applied in prescale)
        int gid = b * 256 + t;
        int node = gid >> 4, sub = gid & 15;
        const float* ep = embed + (size_t)tokens[node] * DIM + sub * 8;
        float4 a = *(const float4*)ep;
        float4 c = *(const float4*)(ep + 4);
        uint4 o;
        o.x = pack2(a.x, a.y); o.y = pack2(a.z, a.w);
        o.z = pack2(c.x, c.y); o.w = pack2(c.z, c.w);
        *(uint4*)(bufH + (size_t)node * DIM + sub * 8) = o;
        return;
    }
    b -= NB_EMB;
    if (b < NB_SENT) {  // esrc sentinel fill + zero bufA sentinel feature row
        int i0 = (b * 256 + t) * 8;
        int4 sv = make_int4(N_NODES, N_NODES, N_NODES, N_NODES);
        if (i0 + 8 <= EPAD) {
            *(int4*)(esrc + i0) = sv;
            *(int4*)(esrc + i0 + 4) = sv;
        } else {
            for (int i = i0; i < EPAD; ++i) esrc[i] = N_NODES;
        }
        if (b == 0 && t < 64)
            ((uint_t*)(bufA + (size_t)N_NODES * DIM))[t] = 0u;
        return;
    }
    b -= NB_SENT;
    if (b < NB_WPREP) {  // W fp32 [k][n] -> bf16 transposed [n][k]
        int i = b * 256 + t;
        int l = i >> 14;
        int idx = i & (DIM * DIM - 1);
        int n = idx >> 7, k = idx & (DIM - 1);
        const float* wsrc = (l == 0) ? w1 : (l == 1) ? w2 : w3;
        wbt[i] = f2bf(wsrc[k * DIM + n]);
        return;
    }
    b -= NB_WPREP;
    {  // coarse histogram of dst>>7: chunk b covers 4096 edges
        for (int k = t; k < NBUCK; k += 256) hh[k] = 0;
        __syncthreads();
        int e0 = b * 4096;
        int e1 = min(e0 + 4096, N_EDGES);
        for (int i = e0 + t; i < e1; i += 256) atomicAdd(&hh[dst[i] >> 7], 1);
        __syncthreads();
        for (int k = t; k < NBUCK; k += 256) G[k * NB_HIST + b] = hh[k];
    }
}

// ---------------- scan of G (bucket-major) -> exclusive Gs ----------------
__global__ void k_scanA(const int* __restrict__ G, int* __restrict__ Gs,
                        int* __restrict__ partials) {
    __shared__ int s[256];
    int t = threadIdx.x;
    int i = blockIdx.x * 256 + t;
    int v = (i < NG) ? G[i] : 0;
    s[t] = v;
    __syncthreads();
    for (int off = 1; off < 256; off <<= 1) {
        int add = (t >= off) ? s[t - off] : 0;
        __syncthreads();
        s[t] += add;
        __syncthreads();
    }
    if (i < NG) Gs[i + 1] = s[t];
    if (t == 255) partials[blockIdx.x] = s[t];
}

__global__ void k_scanB(const int* __restrict__ partials, int* __restrict__ Gs) {
    __shared__ int s[256];
    int t = threadIdx.x;
    int p = 0;
    for (int j = t; j < (int)blockIdx.x; j += 256) p += partials[j];
    s[t] = p;
    __syncthreads();
    for (int off = 128; off > 0; off >>= 1) {
        if (t < off) s[t] += s[t + off];
        __syncthreads();
    }
    int prefix = s[0];
    int i = blockIdx.x * 256 + t;
    if (i < NG) Gs[i + 1] += prefix;
    if (blockIdx.x == 0 && t == 0) Gs[0] = 0;
}

// ---------------- pass 2: coarse scatter into bucket-sorted (Csrc, Cdl) ----------------
__global__ void k_pass2(const int* __restrict__ src, const int* __restrict__ dst,
                        const int* __restrict__ Gs, int* __restrict__ Csrc,
                        uchar_t* __restrict__ Cdl) {
    __shared__ int cur[NBUCK];
    int b = blockIdx.x;  // 391 blocks
    int t = threadIdx.x;
    for (int k = t; k < NBUCK; k += 256) cur[k] = Gs[k * NB_HIST + b];
    __syncthreads();
    int e0 = b * 4096;
    int e1 = min(e0 + 4096, N_EDGES);
    for (int i = e0 + t; i < e1; i += 256) {
        int d = dst[i];
        int slot = atomicAdd(&cur[d >> 7], 1);
        Csrc[slot] = src[i];
        Cdl[slot] = (uchar_t)(d & 127);
    }
}

// ---------------- pass 3: per-bucket fine build: rowptr/pdeg/nd/ns + esrc ----------------
__global__ void k_fine(const int* __restrict__ Csrc, const uchar_t* __restrict__ Cdl,
                       const int* __restrict__ Gs, const int* __restrict__ dego,
                       int* __restrict__ esrc, int* __restrict__ rowptr,
                       int* __restrict__ pdeg, float* __restrict__ ns,
                       float* __restrict__ nd) {
    __shared__ int hcnt[128];
    __shared__ int hstart[128];
    int k = blockIdx.x;  // 782 buckets
    int t = threadIdx.x;
    int node0 = k * 128;
    int nn = min(128, N_NODES - node0);
    int S = Gs[k * NB_HIST];
    int E = Gs[(k + 1) * NB_HIST];
    if (t < 128) hcnt[t] = 0;
    __syncthreads();
    for (int i = S + t; i < E; i += 256) atomicAdd(&hcnt[Cdl[i]], 1);
    __syncthreads();
    if (t == 0) {
        int acc = 0;
        for (int n = 0; n < nn; ++n) {
            hstart[n] = acc;
            acc += (hcnt[n] + 3) & ~3;
        }
    }
    __syncthreads();
    int base = (k * BUCK_RESERVE + S + 3) & ~3;
    if (t < nn) {
        int node = node0 + t;
        rowptr[node] = base + hstart[t];
        pdeg[node] = (hcnt[t] + 3) & ~3;
        nd[node] = rsqrtf(fmaxf((float)hcnt[t], 1.0f));
        ns[node] = rsqrtf(fmaxf((float)dego[node], 1.0f));
    }
    if (k == 0 && t == 0) ns[N_NODES] = 0.f;
    __syncthreads();
    for (int i = S + t; i < E; i += 256) {
        int slot = atomicAdd(&hstart[Cdl[i]], 1);
        esrc[base + slot] = Csrc[i];
    }
}

// ---------------- prescale: x[v] = (BN? relu(fma(y,a,c)) : y) * ns[v], bf16 ----------------
template <int DOBN>
__global__ void k_prescale(const ushort_t* __restrict__ yin, const float* __restrict__ ns,
                           const float* __restrict__ bnsum, const float* __restrict__ bnsq,
                           const float* __restrict__ g, const float* __restrict__ be,
                           ushort_t* __restrict__ xout) {
    __shared__ float sa[DIM], sc[DIM];
    int t = threadIdx.x;
    if (DOBN) {
        if (t < DIM) {
            float mu = bnsum[t] * (1.0f / N_NODES);
            float var = bnsq[t] * (1.0f / N_NODES) - mu * mu;
            float rstd = rsqrtf(var + BN_EPS);
            float a = g[t] * rstd;
            sa[t] = a;
            sc[t] = be[t] - mu * a;
        }
        __syncthreads();
    }
    int gid = blockIdx.x * 256 + t;  // 6250 blocks * 256 = N*16 exactly
    int node = gid >> 4, sub = gid & 15;
    float s = ns[node];
    uint4 u = *(const uint4*)(yin + (size_t)node * DIM + sub * 8);
    float v[8] = {bfl(u.x), bfh(u.x), bfl(u.y), bfh(u.y),
                  bfl(u.z), bfh(u.z), bfl(u.w), bfh(u.w)};
    if (DOBN) {
        const float* a = sa + sub * 8;
        const float* c = sc + sub * 8;
#pragma unroll
        for (int i = 0; i < 8; ++i) v[i] = fmaxf(fmaf(v[i], a[i], c[i]), 0.f);
    }
#pragma unroll
    for (int i = 0; i < 8; ++i) v[i] *= s;
    uint4 o;
    o.x = pack2(v[0], v[1]); o.y = pack2(v[2], v[3]);
    o.z = pack2(v[4], v[5]); o.w = pack2(v[6], v[7]);
    *(uint4*)(xout + (size_t)node * DIM + sub * 8) = o;
}

// ---------------- FUSED pure-sum gather (4-node pipeline) -> LDS -> MFMA + BN stats ----------------
__global__ __launch_bounds__(256) void k_agggemm(const ushort_t* __restrict__ hs,
        const int* __restrict__ rowptr, const int* __restrict__ pdeg,
        const int* __restrict__ esrc, const float* __restrict__ nd,
        const ushort_t* __restrict__ wbt, const float* __restrict__ bias,
        ushort_t* __restrict__ y,
        float* __restrict__ bnsum, float* __restrict__ bnsq) {
    __shared__ ushort_t at[64 * AT_STRIDE];
    __shared__ float csum[DIM], csq[DIM];
    int tid = threadIdx.x;
    if (tid < DIM) { csum[tid] = 0.f; csq[tid] = 0.f; }
    __syncthreads();

    int wave = tid >> 6;
    int lane = tid & 63;
    int bnode = blockIdx.x * 64 + wave * 16;
    int off = lane * 2;

    // prefetch the wave's 16 row starts + padded degrees, serve via shfl
    int rpv = 0, pdv = 0;
    if (lane < 16) {
        int nnode = bnode + lane;
        if (nnode < N_NODES) { rpv = rowptr[nnode]; pdv = pdeg[nnode]; }
    }

#define LD2(s) (*(const uint_t*)(hs + (size_t)(s) * DIM + off))
#define ACC8(I0, I1, X0, Y0, X1, Y1)                                           \
    {                                                                          \
        uint_t u0 = LD2(I0.x), u1 = LD2(I0.y), u2 = LD2(I0.z), u3 = LD2(I0.w); \
        uint_t u4 = LD2(I1.x), u5 = LD2(I1.y), u6 = LD2(I1.z), u7 = LD2(I1.w); \
        X0 += bfl(u0); Y0 += bfh(u0); X1 += bfl(u1); Y1 += bfh(u1);            \
        X0 += bfl(u2); Y0 += bfh(u2); X1 += bfl(u3); Y1 += bfh(u3);            \
        X0 += bfl(u4); Y0 += bfh(u4); X1 += bfl(u5); Y1 += bfh(u5);            \
        X0 += bfl(u6); Y0 += bfh(u6); X1 += bfl(u7); Y1 += bfh(u7);            \
    }
#define ACC4(I0, X0, Y0, X1, Y1)                                               \
    {                                                                          \
        uint_t u0 = LD2(I0.x), u1 = LD2(I0.y), u2 = LD2(I0.z), u3 = LD2(I0.w); \
        X0 += bfl(u0); Y0 += bfh(u0); X1 += bfl(u1); Y1 += bfh(u1);            \
        X0 += bfl(u2); Y0 += bfh(u2); X1 += bfl(u3); Y1 += bfh(u3);            \
    }
#define STEP8(E, X0, Y0, X1, Y1)                                               \
    {                                                                          \
        int4 i0 = *(const int4*)(esrc + E);                                    \
        int4 i1 = *(const int4*)(esrc + E + 4);                                \
        ACC8(i0, i1, X0, Y0, X1, Y1);                                          \
    }

    // ---- phase 1: gather, 4 nodes in flight (32 outstanding row loads) ----
    for (int i = 0; i < 16; i += 4) {
        int eA = __shfl(rpv, i);
        int endA = eA + __shfl(pdv, i);
        int eB = __shfl(rpv, i + 1);
        int endB = eB + __shfl(pdv, i + 1);
        int eC = __shfl(rpv, i + 2);
        int endC = eC + __shfl(pdv, i + 2);
        int eD = __shfl(rpv, i + 3);
        int endD = eD + __shfl(pdv, i + 3);
        float xA0 = 0.f, yA0 = 0.f, xA1 = 0.f, yA1 = 0.f;
        float xB0 = 0.f, yB0 = 0.f, xB1 = 0.f, yB1 = 0.f;
        float xC0 = 0.f, yC0 = 0.f, xC1 = 0.f, yC1 = 0.f;
        float xD0 = 0.f, yD0 = 0.f, xD1 = 0.f, yD1 = 0.f;
        // joint 4-way main loop: 32 loads in flight
        while (eA + 8 <= endA && eB + 8 <= endB && eC + 8 <= endC && eD + 8 <= endD) {
            int4 iA0 = *(const int4*)(esrc + eA);
            int4 iA1 = *(const int4*)(esrc + eA + 4);
            int4 iB0 = *(const int4*)(esrc + eB);
            int4 iB1 = *(const int4*)(esrc + eB + 4);
            int4 iC0 = *(const int4*)(esrc + eC);
            int4 iC1 = *(const int4*)(esrc + eC + 4);
            int4 iD0 = *(const int4*)(esrc + eD);
            int4 iD1 = *(const int4*)(esrc + eD + 4);
            ACC8(iA0, iA1, xA0, yA0, xA1, yA1);
            ACC8(iB0, iB1, xB0, yB0, xB1, yB1);
            ACC8(iC0, iC1, xC0, yC0, xC1, yC1);
            ACC8(iD0, iD1, xD0, yD0, xD1, yD1);
            eA += 8; eB += 8; eC += 8; eD += 8;
        }
        // pair drains (16 in flight)
        while (eA + 8 <= endA && eB + 8 <= endB) {
            STEP8(eA, xA0, yA0, xA1, yA1);
            STEP8(eB, xB0, yB0, xB1, yB1);
            eA += 8; eB += 8;
        }
        while (eC + 8 <= endC && eD + 8 <= endD) {
            STEP8(eC, xC0, yC0, xC1, yC1);
            STEP8(eD, xD0, yD0, xD1, yD1);
            eC += 8; eD += 8;
        }
        // single drains
        for (; eA + 8 <= endA; eA += 8) STEP8(eA, xA0, yA0, xA1, yA1);
        if (eA < endA) { int4 i0 = *(const int4*)(esrc + eA); ACC4(i0, xA0, yA0, xA1, yA1); }
        for (; eB + 8 <= endB; eB += 8) STEP8(eB, xB0, yB0, xB1, yB1);
        if (eB < endB) { int4 i0 = *(const int4*)(esrc + eB); ACC4(i0, xB0, yB0, xB1, yB1); }
        for (; eC + 8 <= endC; eC += 8) STEP8(eC, xC0, yC0, xC1, yC1);
        if (eC < endC) { int4 i0 = *(const int4*)(esrc + eC); ACC4(i0, xC0, yC0, xC1, yC1); }
        for (; eD + 8 <= endD; eD += 8) STEP8(eD, xD0, yD0, xD1, yD1);
        if (eD < endD) { int4 i0 = *(const int4*)(esrc + eD); ACC4(i0, xD0, yD0, xD1, yD1); }
        // finalize 4 nodes
        uint_t ov[4] = {0u, 0u, 0u, 0u};
        if (bnode + i < N_NODES) {
            float n = nd[bnode + i];
            ov[0] = pack2((xA0 + xA1) * n, (yA0 + yA1) * n);
        }
        if (bnode + i + 1 < N_NODES) {
            float n = nd[bnode + i + 1];
            ov[1] = pack2((xB0 + xB1) * n, (yB0 + yB1) * n);
        }
        if (bnode + i + 2 < N_NODES) {
            float n = nd[bnode + i + 2];
            ov[2] = pack2((xC0 + xC1) * n, (yC0 + yC1) * n);
        }
        if (bnode + i + 3 < N_NODES) {
            float n = nd[bnode + i + 3];
            ov[3] = pack2((xD0 + xD1) * n, (yD0 + yD1) * n);
        }
#pragma unroll
        for (int j = 0; j < 4; ++j)
            *(uint_t*)&at[(wave * 16 + i + j) * AT_STRIDE + off] = ov[j];
    }
#undef STEP8
#undef ACC8
#undef ACC4
#undef LD2
    __syncthreads();

    // ---- phase 2: MFMA (D: col=lane&15, row=quad*4+reg) ----
    int m16 = lane & 15;
    int quad = lane >> 4;
    f32x4 acc[8];
#pragma unroll
    for (int nb = 0; nb < 8; ++nb) acc[nb] = (f32x4)(0.f);

    const ushort_t* ap = &at[(wave * 16 + m16) * AT_STRIDE + quad * 8];
#pragma unroll
    for (int k0b = 0; k0b < 4; ++k0b) {
        bf16x8 af = *(const bf16x8*)(ap + k0b * 32);
#pragma unroll
        for (int nb = 0; nb < 8; ++nb) {
            int ncol = nb * 16 + m16;
            bf16x8 bfg = *(const bf16x8*)(wbt + (size_t)ncol * DIM + k0b * 32 + quad * 8);
            acc[nb] = __builtin_amdgcn_mfma_f32_16x16x32_bf16(af, bfg, acc[nb], 0, 0, 0);
        }
    }

    // epilogue: bias, BN partial stats, bf16 store
#pragma unroll
    for (int nb = 0; nb < 8; ++nb) {
        int col = nb * 16 + m16;
        float bcol = bias[col];
        float ps = 0.f, pq = 0.f;
#pragma unroll
        for (int reg = 0; reg < 4; ++reg) {
            int r = bnode + quad * 4 + reg;
            if (r < N_NODES) {
                float v = acc[nb][reg] + bcol;
                ps += v; pq += v * v;
                y[(size_t)r * DIM + col] = f2bf(v);
            }
        }
        atomicAdd(&csum[col], ps);
        atomicAdd(&csq[col], pq);
    }
    __syncthreads();
    if (tid < DIM) {
        atomicAdd(&bnsum[tid], csum[tid]);
        atomicAdd(&bnsq[tid], csq[tid]);
    }
}

// ---------------- pooling: fused layer-3 BN fold+apply + graph counts ----------------
#define POOL_NODES 128
__global__ void k_pool(const ushort_t* __restrict__ yin, const int* __restrict__ gids,
                       const float* __restrict__ bnsum, const float* __restrict__ bnsq,
                       const float* __restrict__ g, const float* __restrict__ be,
                       float* __restrict__ pool, int* __restrict__ cnt) {
    __shared__ int h[N_GRAPHS];
    int col = threadIdx.x;  // 128
    float mu = bnsum[col] * (1.0f / N_NODES);
    float var = bnsq[col] * (1.0f / N_NODES) - mu * mu;
    float rstd = rsqrtf(var + BN_EPS);
    float a = g[col] * rstd;
    float c = be[col] - mu * a;
    if (col < N_GRAPHS) h[col] = 0;
    __syncthreads();
    int base = blockIdx.x * POOL_NODES;
    int end = min(base + POOL_NODES, N_NODES);
    for (int n = base + col; n < end; n += 128) atomicAdd(&h[gids[n]], 1);
    __syncthreads();
    if (col < N_GRAPHS && h[col]) atomicAdd(&cnt[col], h[col]);
    float acc = 0.f;
    int cur = gids[base];
    for (int n = base; n < end; ++n) {
        int gg = gids[n];
        if (gg != cur) {
            atomicAdd(&pool[(size_t)cur * DIM + col], acc);
            acc = 0.f;
            cur = gg;
        }
        uint_t u = *(const uint_t*)(yin + (size_t)n * DIM + (col & ~1));
        float v = (col & 1) ? bfh(u) : bfl(u);
        acc += fmaxf(fmaf(v, a, c), 0.f);
    }
    atomicAdd(&pool[(size_t)cur * DIM + col], acc);
}

// ---------------- final FC (one block per graph) ----------------
__global__ void k_final(const float* __restrict__ pool, const int* __restrict__ cnt,
                        const float* __restrict__ fcW1, const float* __restrict__ fcb1,
                        const float* __restrict__ fcW2, const float* __restrict__ fcb2,
                        float* __restrict__ out) {
    __shared__ float hg[DIM];
    __shared__ float z[64];
    int g = blockIdx.x;
    int t = threadIdx.x;  // 128
    float cf = fmaxf((float)cnt[g], 1.0f);
    hg[t] = pool[(size_t)g * DIM + t] / cf;
    __syncthreads();
    if (t < 64) {
        float acc = fcb1[t];
        for (int k = 0; k < DIM; ++k)
            acc += hg[k] * fcW1[k * 64 + t];
        z[t] = fmaxf(acc, 0.f);
    }
    __syncthreads();
    if (t < 2) {
        float acc = fcb2[t];
        for (int k = 0; k < 64; ++k)
            acc += z[k] * fcW2[k * 2 + t];
        out[g * 2 + t] = acc;
    }
}

extern "C" void kernel_launch(void* const* d_in, const int* in_sizes, int n_in,
                              void* d_out, int out_size, void* d_ws, size_t ws_size,
                              hipStream_t stream) {
    const int* tokens = (const int*)d_in[0];
    const int* src = (const int*)d_in[1];
    const int* dst = (const int*)d_in[2];
    const int* gids = (const int*)d_in[3];
    const float* embed = (const float*)d_in[4];
    const float* W1 = (const float*)d_in[5];
    const float* b1 = (const float*)d_in[6];
    const float* g1 = (const float*)d_in[7];
    const float* be1 = (const float*)d_in[8];
    const float* W2 = (const float*)d_in[9];
    const float* b2 = (const float*)d_in[10];
    const float* g2 = (const float*)d_in[11];
    const float* be2 = (const float*)d_in[12];
    const float* W3 = (const float*)d_in[13];
    const float* b3 = (const float*)d_in[14];
    const float* g3 = (const float*)d_in[15];
    const float* be3 = (const float*)d_in[16];
    const float* fcW1 = (const float*)d_in[17];
    const float* fcb1 = (const float*)d_in[18];
    const float* fcW2 = (const float*)d_in[19];
    const float* fcb2 = (const float*)d_in[20];
    float* out = (float*)d_out;

    char* w = (char*)d_ws;
    auto alloc = [&](size_t bytes) {
        void* p = (void*)w;
        w += (bytes + 255) & ~(size_t)255;
        return p;
    };
    ushort_t* bufH = (ushort_t*)alloc((size_t)(N_NODES + 1) * DIM * 2);  // embed raw / y2
    ushort_t* bufA = (ushort_t*)alloc((size_t)(N_NODES + 1) * DIM * 2);  // prescaled gather input
    ushort_t* bufY = (ushort_t*)alloc((size_t)(N_NODES + 1) * DIM * 2);  // y1 / y3
    int* esrc = (int*)alloc((size_t)EPAD * 4);
    int* rowptr = (int*)alloc((size_t)N_NODES * 4);
    int* pdeg = (int*)alloc((size_t)N_NODES * 4);
    float* ns = (float*)alloc((size_t)(N_NODES + 1) * 4);
    float* nd = (float*)alloc((size_t)N_NODES * 4);
    ushort_t* wbt = (ushort_t*)alloc(3 * DIM * DIM * 2);
    int* G = (int*)alloc((size_t)NG * 4);
    int* Gs = (int*)alloc((size_t)(NG + 1) * 4);
    int* partials = (int*)alloc(2048 * 4);
    int* Csrc = (int*)alloc((size_t)N_EDGES * 4);
    uchar_t* Cdl = (uchar_t*)alloc((size_t)N_EDGES);
    // zeroed region (contiguous)
    char* zstart = w;
    int* dego = (int*)alloc((size_t)N_NODES * 4);
    float* bnsum = (float*)alloc(3 * DIM * 4);
    float* bnsq = (float*)alloc(3 * DIM * 4);
    float* pool = (float*)alloc((size_t)N_GRAPHS * DIM * 4);
    int* cnt = (int*)alloc((size_t)N_GRAPHS * 4);
    int zwords = (int)((size_t)(w - zstart) / 4);

    k_zero<<<(zwords + 255) / 256, 256, 0, stream>>>((int*)zstart, zwords);
    k_front<<<NB_DEG + NB_EMB + NB_SENT + NB_WPREP + NB_HIST, 256, 0, stream>>>(
        src, dst, dego, tokens, embed, bufH, bufA, esrc, W1, W2, W3, wbt, G);
    k_scanA<<<NB_SCANG, 256, 0, stream>>>(G, Gs, partials);
    k_scanB<<<NB_SCANG, 256, 0, stream>>>(partials, Gs);
    k_pass2<<<NB_HIST, 256, 0, stream>>>(src, dst, Gs, Csrc, Cdl);
    k_fine<<<NBUCK, 256, 0, stream>>>(Csrc, Cdl, Gs, dego, esrc, rowptr, pdeg, ns, nd);

    int nb_fused = (N_NODES + 63) / 64;
    int nb_ps = 6250;  // N*16/256

    // l=0: prescale bufH -> bufA; gather bufA -> y1 in bufY
    k_prescale<0><<<nb_ps, 256, 0, stream>>>(bufH, ns, nullptr, nullptr, nullptr, nullptr, bufA);
    k_agggemm<<<nb_fused, 256, 0, stream>>>(bufA, rowptr, pdeg, esrc, nd,
                                            wbt, b1, bufY, bnsum, bnsq);
    // l=1: prescale bufY (BN stats1) -> bufA; gather -> y2 in bufH
    k_prescale<1><<<nb_ps, 256, 0, stream>>>(bufY, ns, bnsum, bnsq, g1, be1, bufA);
    k_agggemm<<<nb_fused, 256, 0, stream>>>(bufA, rowptr, pdeg, esrc, nd,
                                            wbt + (size_t)DIM * DIM, b2, bufH,
                                            bnsum + DIM, bnsq + DIM);
    // l=2: prescale bufH (BN stats2) -> bufA; gather -> y3 in bufY
    k_prescale<1><<<nb_ps, 256, 0, stream>>>(bufH, ns, bnsum + DIM, bnsq + DIM, g2, be2, bufA);
    k_agggemm<<<nb_fused, 256, 0, stream>>>(bufA, rowptr, pdeg, esrc, nd,
                                            wbt + (size_t)2 * DIM * DIM, b3, bufY,
                                            bnsum + 2 * DIM, bnsq + 2 * DIM);

    k_pool<<<(N_NODES + POOL_NODES - 1) / POOL_NODES, DIM, 0, stream>>>(
        bufY, gids, bnsum + 2 * DIM, bnsq + 2 * DIM, g3, be3, pool, cnt);
    k_final<<<N_GRAPHS, DIM, 0, stream>>>(pool, cnt, fcW1, fcb1, fcW2, fcb2, out);
}

// Round 17
// 690.199 us; speedup vs baseline: 1.1143x; 1.1143x over previous
//
#include <hip/hip_runtime.h>

#define N_NODES 100000
#define N_EDGES 1600000
#define N_GRAPHS 64
#define DIM 128
#define BN_EPS 1e-5f
#define EPAD 2000000          // sentinel-filled esrc capacity (needs 1,903,419)

#define NB_DEG 6250           // dego atomics: 6250*256 = 1.6M edges
#define NB_EMB 6250           // embed: 100k nodes * 16 thr
#define NB_SENT 977           // esrc sentinel fill, 8 per thread
#define NB_WPREP 192          // 3*128*128/256
#define NB_HIST 391           // coarse hist: 391 chunks * 4096 edges
#define NBUCK 782             // coarse buckets = dst>>7 (100000/128)
#define NG (NBUCK * NB_HIST)  // count-matrix size = 305762
#define NB_SCANG 1195         // ceil(NG/256)
#define BUCK_RESERVE 388      // cnt + 128*3 pad + 4 align slack

#define AT_STRIDE 136  // 128 + 8 pad: 2-way-only LDS bank aliasing

typedef unsigned short ushort_t;
typedef unsigned char uchar_t;
typedef unsigned int uint_t;
typedef __attribute__((ext_vector_type(8))) short bf16x8;
typedef __attribute__((ext_vector_type(4))) float f32x4;

__device__ __forceinline__ float bfl(uint_t u) {
    union { uint_t i; float f; } v; v.i = u << 16; return v.f;
}
__device__ __forceinline__ float bfh(uint_t u) {
    union { uint_t i; float f; } v; v.i = u & 0xffff0000u; return v.f;
}
__device__ __forceinline__ ushort_t f2bf(float f) {
    union { float f; uint_t i; } v; v.f = f;
    uint_t x = v.i;
    return (ushort_t)((x + 0x7fffu + ((x >> 16) & 1u)) >> 16);
}
__device__ __forceinline__ uint_t pack2(float lo, float hi) {
    return ((uint_t)f2bf(hi) << 16) | (uint_t)f2bf(lo);
}

// ---------------- zero scratch ----------------
__global__ void k_zero(int* __restrict__ p, int n) {
    int i = blockIdx.x * blockDim.x + threadIdx.x;
    if (i < n) p[i] = 0;
}

// ---------------- front mega-kernel: {dego | embed | sentinel | wprep | coarse-hist} ----------------
__global__ void k_front(const int* __restrict__ src, const int* __restrict__ dst,
                        int* __restrict__ dego,
                        const int* __restrict__ tokens, const float* __restrict__ embed,
                        ushort_t* __restrict__ bufH, ushort_t* __restrict__ bufA,
                        int* __restrict__ esrc,
                        const float* __restrict__ w1, const float* __restrict__ w2,
                        const float* __restrict__ w3, ushort_t* __restrict__ wbt,
                        int* __restrict__ G) {
    __shared__ int hh[NBUCK];
    int b = blockIdx.x;
    int t = threadIdx.x;
    if (b < NB_DEG) {
        int e = b * 256 + t;
        if (e < N_EDGES) atomicAdd(&dego[src[e]], 1);
        return;
    }
    b -= NB_DEG;
    if (b < NB_EMB) {  // raw embedding gather (ns applied in prescale)
        int gid = b * 256 + t;
        int node = gid >> 4, sub = gid & 15;
        const float* ep = embed + (size_t)tokens[node] * DIM + sub * 8;
        float4 a = *(const float4*)ep;
        float4 c = *(const float4*)(ep + 4);
        uint4 o;
        o.x = pack2(a.x, a.y); o.y = pack2(a.z, a.w);
        o.z = pack2(c.x, c.y); o.w = pack2(c.z, c.w);
        *(uint4*)(bufH + (size_t)node * DIM + sub * 8) = o;
        return;
    }
    b -= NB_EMB;
    if (b < NB_SENT) {  // esrc sentinel fill + zero bufA sentinel feature row
        int i0 = (b * 256 + t) * 8;
        int4 sv = make_int4(N_NODES, N_NODES, N_NODES, N_NODES);
        if (i0 + 8 <= EPAD) {
            *(int4*)(esrc + i0) = sv;
            *(int4*)(esrc + i0 + 4) = sv;
        } else {
            for (int i = i0; i < EPAD; ++i) esrc[i] = N_NODES;
        }
        if (b == 0 && t < 64)
            ((uint_t*)(bufA + (size_t)N_NODES * DIM))[t] = 0u;
        return;
    }
    b -= NB_SENT;
    if (b < NB_WPREP) {  // W fp32 [k][n] -> bf16 transposed [n][k]
        int i = b * 256 + t;
        int l = i >> 14;
        int idx = i & (DIM * DIM - 1);
        int n = idx >> 7, k = idx & (DIM - 1);
        const float* wsrc = (l == 0) ? w1 : (l == 1) ? w2 : w3;
        wbt[i] = f2bf(wsrc[k * DIM + n]);
        return;
    }
    b -= NB_WPREP;
    {  // coarse histogram of dst>>7: chunk b covers 4096 edges
        for (int k = t; k < NBUCK; k += 256) hh[k] = 0;
        __syncthreads();
        int e0 = b * 4096;
        int e1 = min(e0 + 4096, N_EDGES);
        for (int i = e0 + t; i < e1; i += 256) atomicAdd(&hh[dst[i] >> 7], 1);
        __syncthreads();
        for (int k = t; k < NBUCK; k += 256) G[k * NB_HIST + b] = hh[k];
    }
}

// ---------------- scan of G (bucket-major) -> exclusive Gs ----------------
__global__ void k_scanA(const int* __restrict__ G, int* __restrict__ Gs,
                        int* __restrict__ partials) {
    __shared__ int s[256];
    int t = threadIdx.x;
    int i = blockIdx.x * 256 + t;
    int v = (i < NG) ? G[i] : 0;
    s[t] = v;
    __syncthreads();
    for (int off = 1; off < 256; off <<= 1) {
        int add = (t >= off) ? s[t - off] : 0;
        __syncthreads();
        s[t] += add;
        __syncthreads();
    }
    if (i < NG) Gs[i + 1] = s[t];
    if (t == 255) partials[blockIdx.x] = s[t];
}

__global__ void k_scanB(const int* __restrict__ partials, int* __restrict__ Gs) {
    __shared__ int s[256];
    int t = threadIdx.x;
    int p = 0;
    for (int j = t; j < (int)blockIdx.x; j += 256) p += partials[j];
    s[t] = p;
    __syncthreads();
    for (int off = 128; off > 0; off >>= 1) {
        if (t < off) s[t] += s[t + off];
        __syncthreads();
    }
    int prefix = s[0];
    int i = blockIdx.x * 256 + t;
    if (i < NG) Gs[i + 1] += prefix;
    if (blockIdx.x == 0 && t == 0) Gs[0] = 0;
}

// ---------------- pass 2: coarse scatter into bucket-sorted (Csrc, Cdl) ----------------
__global__ void k_pass2(const int* __restrict__ src, const int* __restrict__ dst,
                        const int* __restrict__ Gs, int* __restrict__ Csrc,
                        uchar_t* __restrict__ Cdl) {
    __shared__ int cur[NBUCK];
    int b = blockIdx.x;  // 391 blocks
    int t = threadIdx.x;
    for (int k = t; k < NBUCK; k += 256) cur[k] = Gs[k * NB_HIST + b];
    __syncthreads();
    int e0 = b * 4096;
    int e1 = min(e0 + 4096, N_EDGES);
    for (int i = e0 + t; i < e1; i += 256) {
        int d = dst[i];
        int slot = atomicAdd(&cur[d >> 7], 1);
        Csrc[slot] = src[i];
        Cdl[slot] = (uchar_t)(d & 127);
    }
}

// ---------------- pass 3: per-bucket fine build: rowptr/pdeg/nd/ns + esrc ----------------
__global__ void k_fine(const int* __restrict__ Csrc, const uchar_t* __restrict__ Cdl,
                       const int* __restrict__ Gs, const int* __restrict__ dego,
                       int* __restrict__ esrc, int* __restrict__ rowptr,
                       int* __restrict__ pdeg, float* __restrict__ ns,
                       float* __restrict__ nd) {
    __shared__ int hcnt[128];
    __shared__ int hstart[128];
    int k = blockIdx.x;  // 782 buckets
    int t = threadIdx.x;
    int node0 = k * 128;
    int nn = min(128, N_NODES - node0);
    int S = Gs[k * NB_HIST];
    int E = Gs[(k + 1) * NB_HIST];
    if (t < 128) hcnt[t] = 0;
    __syncthreads();
    for (int i = S + t; i < E; i += 256) atomicAdd(&hcnt[Cdl[i]], 1);
    __syncthreads();
    if (t == 0) {
        int acc = 0;
        for (int n = 0; n < nn; ++n) {
            hstart[n] = acc;
            acc += (hcnt[n] + 3) & ~3;
        }
    }
    __syncthreads();
    int base = (k * BUCK_RESERVE + S + 3) & ~3;
    if (t < nn) {
        int node = node0 + t;
        rowptr[node] = base + hstart[t];
        pdeg[node] = (hcnt[t] + 3) & ~3;
        nd[node] = rsqrtf(fmaxf((float)hcnt[t], 1.0f));
        ns[node] = rsqrtf(fmaxf((float)dego[node], 1.0f));
    }
    if (k == 0 && t == 0) ns[N_NODES] = 0.f;
    __syncthreads();
    for (int i = S + t; i < E; i += 256) {
        int slot = atomicAdd(&hstart[Cdl[i]], 1);
        esrc[base + slot] = Csrc[i];
    }
}

// ---------------- prescale: x[v] = (BN? relu(fma(y,a,c)) : y) * ns[v], bf16 ----------------
template <int DOBN>
__global__ void k_prescale(const ushort_t* __restrict__ yin, const float* __restrict__ ns,
                           const float* __restrict__ bnsum, const float* __restrict__ bnsq,
                           const float* __restrict__ g, const float* __restrict__ be,
                           ushort_t* __restrict__ xout) {
    __shared__ float sa[DIM], sc[DIM];
    int t = threadIdx.x;
    if (DOBN) {
        if (t < DIM) {
            float mu = bnsum[t] * (1.0f / N_NODES);
            float var = bnsq[t] * (1.0f / N_NODES) - mu * mu;
            float rstd = rsqrtf(var + BN_EPS);
            float a = g[t] * rstd;
            sa[t] = a;
            sc[t] = be[t] - mu * a;
        }
        __syncthreads();
    }
    int gid = blockIdx.x * 256 + t;  // 6250 blocks * 256 = N*16 exactly
    int node = gid >> 4, sub = gid & 15;
    float s = ns[node];
    uint4 u = *(const uint4*)(yin + (size_t)node * DIM + sub * 8);
    float v[8] = {bfl(u.x), bfh(u.x), bfl(u.y), bfh(u.y),
                  bfl(u.z), bfh(u.z), bfl(u.w), bfh(u.w)};
    if (DOBN) {
        const float* a = sa + sub * 8;
        const float* c = sc + sub * 8;
#pragma unroll
        for (int i = 0; i < 8; ++i) v[i] = fmaxf(fmaf(v[i], a[i], c[i]), 0.f);
    }
#pragma unroll
    for (int i = 0; i < 8; ++i) v[i] *= s;
    uint4 o;
    o.x = pack2(v[0], v[1]); o.y = pack2(v[2], v[3]);
    o.z = pack2(v[4], v[5]); o.w = pack2(v[6], v[7]);
    *(uint4*)(xout + (size_t)node * DIM + sub * 8) = o;
}

// ---------------- FUSED pure-sum gather (2-node pipeline) -> LDS -> MFMA + BN stats.
// Barrier-free until the final stats reduce: the A-tile and csum/csq rows are
// wave-private, so waves flow gather->MFMA->store independently. ----------------
__global__ __launch_bounds__(256) void k_agggemm(const ushort_t* __restrict__ hs,
        const int* __restrict__ rowptr, const int* __restrict__ pdeg,
        const int* __restrict__ esrc, const float* __restrict__ nd,
        const ushort_t* __restrict__ wbt, const float* __restrict__ bias,
        ushort_t* __restrict__ y,
        float* __restrict__ bnsum, float* __restrict__ bnsq) {
    __shared__ ushort_t at[64 * AT_STRIDE];
    __shared__ float csum[4][DIM], csq[4][DIM];  // per-wave rows
    int tid = threadIdx.x;
    int wave = tid >> 6;
    int lane = tid & 63;
    // per-wave stats init (no barrier needed: rows are wave-private)
    csum[wave][lane] = 0.f;
    csum[wave][lane + 64] = 0.f;
    csq[wave][lane] = 0.f;
    csq[wave][lane + 64] = 0.f;

    int bnode = blockIdx.x * 64 + wave * 16;
    int off = lane * 2;

    // prefetch the wave's 16 row starts + padded degrees, serve via shfl
    int rpv = 0, pdv = 0;
    if (lane < 16) {
        int nnode = bnode + lane;
        if (nnode < N_NODES) { rpv = rowptr[nnode]; pdv = pdeg[nnode]; }
    }

#define LD2(s) (*(const uint_t*)(hs + (size_t)(s) * DIM + off))
#define ACC8(I0, I1, X0, Y0, X1, Y1)                                           \
    {                                                                          \
        uint_t u0 = LD2(I0.x), u1 = LD2(I0.y), u2 = LD2(I0.z), u3 = LD2(I0.w); \
        uint_t u4 = LD2(I1.x), u5 = LD2(I1.y), u6 = LD2(I1.z), u7 = LD2(I1.w); \
        X0 += bfl(u0); Y0 += bfh(u0); X1 += bfl(u1); Y1 += bfh(u1);            \
        X0 += bfl(u2); Y0 += bfh(u2); X1 += bfl(u3); Y1 += bfh(u3);            \
        X0 += bfl(u4); Y0 += bfh(u4); X1 += bfl(u5); Y1 += bfh(u5);            \
        X0 += bfl(u6); Y0 += bfh(u6); X1 += bfl(u7); Y1 += bfh(u7);            \
    }
#define ACC4(I0, X0, Y0, X1, Y1)                                               \
    {                                                                          \
        uint_t u0 = LD2(I0.x), u1 = LD2(I0.y), u2 = LD2(I0.z), u3 = LD2(I0.w); \
        X0 += bfl(u0); Y0 += bfh(u0); X1 += bfl(u1); Y1 += bfh(u1);            \
        X0 += bfl(u2); Y0 += bfh(u2); X1 += bfl(u3); Y1 += bfh(u3);            \
    }

    // ---- phase 1: gather, 2 nodes in flight (16 outstanding row loads) ----
    for (int i = 0; i < 16; i += 2) {
        int nodeA = bnode + i;
        int nodeB = bnode + i + 1;
        int eA = __shfl(rpv, i);
        int endA = eA + __shfl(pdv, i);
        int eB = __shfl(rpv, i + 1);
        int endB = eB + __shfl(pdv, i + 1);
        float xA0 = 0.f, yA0 = 0.f, xA1 = 0.f, yA1 = 0.f;
        float xB0 = 0.f, yB0 = 0.f, xB1 = 0.f, yB1 = 0.f;
        // joint main loop: 16 loads in flight
        while (eA + 8 <= endA && eB + 8 <= endB) {
            int4 iA0 = *(const int4*)(esrc + eA);
            int4 iA1 = *(const int4*)(esrc + eA + 4);
            int4 iB0 = *(const int4*)(esrc + eB);
            int4 iB1 = *(const int4*)(esrc + eB + 4);
            ACC8(iA0, iA1, xA0, yA0, xA1, yA1);
            ACC8(iB0, iB1, xB0, yB0, xB1, yB1);
            eA += 8; eB += 8;
        }
        // drain A
        for (; eA + 8 <= endA; eA += 8) {
            int4 i0 = *(const int4*)(esrc + eA);
            int4 i1 = *(const int4*)(esrc + eA + 4);
            ACC8(i0, i1, xA0, yA0, xA1, yA1);
        }
        if (eA < endA) {  // exactly 4 (rows padded to x4)
            int4 i0 = *(const int4*)(esrc + eA);
            ACC4(i0, xA0, yA0, xA1, yA1);
        }
        // drain B
        for (; eB + 8 <= endB; eB += 8) {
            int4 i0 = *(const int4*)(esrc + eB);
            int4 i1 = *(const int4*)(esrc + eB + 4);
            ACC8(i0, i1, xB0, yB0, xB1, yB1);
        }
        if (eB < endB) {
            int4 i0 = *(const int4*)(esrc + eB);
            ACC4(i0, xB0, yB0, xB1, yB1);
        }
        // finalize both nodes
        uint_t ovA = 0u, ovB = 0u;
        if (nodeA < N_NODES) {
            float n = nd[nodeA];
            ovA = pack2((xA0 + xA1) * n, (yA0 + yA1) * n);
        }
        if (nodeB < N_NODES) {
            float n = nd[nodeB];
            ovB = pack2((xB0 + xB1) * n, (yB0 + yB1) * n);
        }
        *(uint_t*)&at[(wave * 16 + i) * AT_STRIDE + off] = ovA;
        *(uint_t*)&at[(wave * 16 + i + 1) * AT_STRIDE + off] = ovB;
    }
#undef ACC8
#undef ACC4
#undef LD2
    // NO barrier: each wave's MFMA reads only its own 16 LDS rows.

    // ---- phase 2: MFMA (D: col=lane&15, row=quad*4+reg) ----
    int m16 = lane & 15;
    int quad = lane >> 4;
    f32x4 acc[8];
#pragma unroll
    for (int nb = 0; nb < 8; ++nb) acc[nb] = (f32x4)(0.f);

    const ushort_t* ap = &at[(wave * 16 + m16) * AT_STRIDE + quad * 8];
#pragma unroll
    for (int k0b = 0; k0b < 4; ++k0b) {
        bf16x8 af = *(const bf16x8*)(ap + k0b * 32);
#pragma unroll
        for (int nb = 0; nb < 8; ++nb) {
            int ncol = nb * 16 + m16;
            bf16x8 bfg = *(const bf16x8*)(wbt + (size_t)ncol * DIM + k0b * 32 + quad * 8);
            acc[nb] = __builtin_amdgcn_mfma_f32_16x16x32_bf16(af, bfg, acc[nb], 0, 0, 0);
        }
    }

    // epilogue: bias, per-wave BN partial stats, bf16 store
#pragma unroll
    for (int nb = 0; nb < 8; ++nb) {
        int col = nb * 16 + m16;
        float bcol = bias[col];
        float ps = 0.f, pq = 0.f;
#pragma unroll
        for (int reg = 0; reg < 4; ++reg) {
            int r = bnode + quad * 4 + reg;
            if (r < N_NODES) {
                float v = acc[nb][reg] + bcol;
                ps += v; pq += v * v;
                y[(size_t)r * DIM + col] = f2bf(v);
            }
        }
        atomicAdd(&csum[wave][col], ps);
        atomicAdd(&csq[wave][col], pq);
    }
    __syncthreads();  // single barrier: cross-wave stats reduce
    if (tid < DIM) {
        float s = csum[0][tid] + csum[1][tid] + csum[2][tid] + csum[3][tid];
        float q = csq[0][tid] + csq[1][tid] + csq[2][tid] + csq[3][tid];
        atomicAdd(&bnsum[tid], s);
        atomicAdd(&bnsq[tid], q);
    }
}

// ---------------- pooling: fused layer-3 BN fold+apply + graph counts ----------------
#define POOL_NODES 128
__global__ void k_pool(const ushort_t* __restrict__ yin, const int* __restrict__ gids,
                       const float* __restrict__ bnsum, const float* __restrict__ bnsq,
                       const float* __restrict__ g, const float* __restrict__ be,
                       float* __restrict__ pool, int* __restrict__ cnt) {
    __shared__ int h[N_GRAPHS];
    int col = threadIdx.x;  // 128
    float mu = bnsum[col] * (1.0f / N_NODES);
    float var = bnsq[col] * (1.0f / N_NODES) - mu * mu;
    float rstd = rsqrtf(var + BN_EPS);
    float a = g[col] * rstd;
    float c = be[col] - mu * a;
    if (col < N_GRAPHS) h[col] = 0;
    __syncthreads();
    int base = blockIdx.x * POOL_NODES;
    int end = min(base + POOL_NODES, N_NODES);
    for (int n = base + col; n < end; n += 128) atomicAdd(&h[gids[n]], 1);
    __syncthreads();
    if (col < N_GRAPHS && h[col]) atomicAdd(&cnt[col], h[col]);
    float acc = 0.f;
    int cur = gids[base];
    for (int n = base; n < end; ++n) {
        int gg = gids[n];
        if (gg != cur) {
            atomicAdd(&pool[(size_t)cur * DIM + col], acc);
            acc = 0.f;
            cur = gg;
        }
        uint_t u = *(const uint_t*)(yin + (size_t)n * DIM + (col & ~1));
        float v = (col & 1) ? bfh(u) : bfl(u);
        acc += fmaxf(fmaf(v, a, c), 0.f);
    }
    atomicAdd(&pool[(size_t)cur * DIM + col], acc);
}

// ---------------- final FC (one block per graph) ----------------
__global__ void k_final(const float* __restrict__ pool, const int* __restrict__ cnt,
                        const float* __restrict__ fcW1, const float* __restrict__ fcb1,
                        const float* __restrict__ fcW2, const float* __restrict__ fcb2,
                        float* __restrict__ out) {
    __shared__ float hg[DIM];
    __shared__ float z[64];
    int g = blockIdx.x;
    int t = threadIdx.x;  // 128
    float cf = fmaxf((float)cnt[g], 1.0f);
    hg[t] = pool[(size_t)g * DIM + t] / cf;
    __syncthreads();
    if (t < 64) {
        float acc = fcb1[t];
        for (int k = 0; k < DIM; ++k)
            acc += hg[k] * fcW1[k * 64 + t];
        z[t] = fmaxf(acc, 0.f);
    }
    __syncthreads();
    if (t < 2) {
        float acc = fcb2[t];
        for (int k = 0; k < 64; ++k)
            acc += z[k] * fcW2[k * 2 + t];
        out[g * 2 + t] = acc;
    }
}

extern "C" void kernel_launch(void* const* d_in, const int* in_sizes, int n_in,
                              void* d_out, int out_size, void* d_ws, size_t ws_size,
                              hipStream_t stream) {
    const int* tokens = (const int*)d_in[0];
    const int* src = (const int*)d_in[1];
    const int* dst = (const int*)d_in[2];
    const int* gids = (const int*)d_in[3];
    const float* embed = (const float*)d_in[4];
    const float* W1 = (const float*)d_in[5];
    const float* b1 = (const float*)d_in[6];
    const float* g1 = (const float*)d_in[7];
    const float* be1 = (const float*)d_in[8];
    const float* W2 = (const float*)d_in[9];
    const float* b2 = (const float*)d_in[10];
    const float* g2 = (const float*)d_in[11];
    const float* be2 = (const float*)d_in[12];
    const float* W3 = (const float*)d_in[13];
    const float* b3 = (const float*)d_in[14];
    const float* g3 = (const float*)d_in[15];
    const float* be3 = (const float*)d_in[16];
    const float* fcW1 = (const float*)d_in[17];
    const float* fcb1 = (const float*)d_in[18];
    const float* fcW2 = (const float*)d_in[19];
    const float* fcb2 = (const float*)d_in[20];
    float* out = (float*)d_out;

    char* w = (char*)d_ws;
    auto alloc = [&](size_t bytes) {
        void* p = (void*)w;
        w += (bytes + 255) & ~(size_t)255;
        return p;
    };
    ushort_t* bufH = (ushort_t*)alloc((size_t)(N_NODES + 1) * DIM * 2);  // embed raw / y2
    ushort_t* bufA = (ushort_t*)alloc((size_t)(N_NODES + 1) * DIM * 2);  // prescaled gather input
    ushort_t* bufY = (ushort_t*)alloc((size_t)(N_NODES + 1) * DIM * 2);  // y1 / y3
    int* esrc = (int*)alloc((size_t)EPAD * 4);
    int* rowptr = (int*)alloc((size_t)N_NODES * 4);
    int* pdeg = (int*)alloc((size_t)N_NODES * 4);
    float* ns = (float*)alloc((size_t)(N_NODES + 1) * 4);
    float* nd = (float*)alloc((size_t)N_NODES * 4);
    ushort_t* wbt = (ushort_t*)alloc(3 * DIM * DIM * 2);
    int* G = (int*)alloc((size_t)NG * 4);
    int* Gs = (int*)alloc((size_t)(NG + 1) * 4);
    int* partials = (int*)alloc(2048 * 4);
    int* Csrc = (int*)alloc((size_t)N_EDGES * 4);
    uchar_t* Cdl = (uchar_t*)alloc((size_t)N_EDGES);
    // zeroed region (contiguous)
    char* zstart = w;
    int* dego = (int*)alloc((size_t)N_NODES * 4);
    float* bnsum = (float*)alloc(3 * DIM * 4);
    float* bnsq = (float*)alloc(3 * DIM * 4);
    float* pool = (float*)alloc((size_t)N_GRAPHS * DIM * 4);
    int* cnt = (int*)alloc((size_t)N_GRAPHS * 4);
    int zwords = (int)((size_t)(w - zstart) / 4);

    k_zero<<<(zwords + 255) / 256, 256, 0, stream>>>((int*)zstart, zwords);
    k_front<<<NB_DEG + NB_EMB + NB_SENT + NB_WPREP + NB_HIST, 256, 0, stream>>>(
        src, dst, dego, tokens, embed, bufH, bufA, esrc, W1, W2, W3, wbt, G);
    k_scanA<<<NB_SCANG, 256, 0, stream>>>(G, Gs, partials);
    k_scanB<<<NB_SCANG, 256, 0, stream>>>(partials, Gs);
    k_pass2<<<NB_HIST, 256, 0, stream>>>(src, dst, Gs, Csrc, Cdl);
    k_fine<<<NBUCK, 256, 0, stream>>>(Csrc, Cdl, Gs, dego, esrc, rowptr, pdeg, ns, nd);

    int nb_fused = (N_NODES + 63) / 64;
    int nb_ps = 6250;  // N*16/256

    // l=0: prescale bufH -> bufA; gather bufA -> y1 in bufY
    k_prescale<0><<<nb_ps, 256, 0, stream>>>(bufH, ns, nullptr, nullptr, nullptr, nullptr, bufA);
    k_agggemm<<<nb_fused, 256, 0, stream>>>(bufA, rowptr, pdeg, esrc, nd,
                                            wbt, b1, bufY, bnsum, bnsq);
    // l=1: prescale bufY (BN stats1) -> bufA; gather -> y2 in bufH
    k_prescale<1><<<nb_ps, 256, 0, stream>>>(bufY, ns, bnsum, bnsq, g1, be1, bufA);
    k_agggemm<<<nb_fused, 256, 0, stream>>>(bufA, rowptr, pdeg, esrc, nd,
                                            wbt + (size_t)DIM * DIM, b2, bufH,
                                            bnsum + DIM, bnsq + DIM);
    // l=2: prescale bufH (BN stats2) -> bufA; gather -> y3 in bufY
    k_prescale<1><<<nb_ps, 256, 0, stream>>>(bufH, ns, bnsum + DIM, bnsq + DIM, g2, be2, bufA);
    k_agggemm<<<nb_fused, 256, 0, stream>>>(bufA, rowptr, pdeg, esrc, nd,
                                            wbt + (size_t)2 * DIM * DIM, b3, bufY,
                                            bnsum + 2 * DIM, bnsq + 2 * DIM);

    k_pool<<<(N_NODES + POOL_NODES - 1) / POOL_NODES, DIM, 0, stream>>>(
        bufY, gids, bnsum + 2 * DIM, bnsq + 2 * DIM, g3, be3, pool, cnt);
    k_final<<<N_GRAPHS, DIM, 0, stream>>>(pool, cnt, fcW1, fcb1, fcW2, fcb2, out);
}

// Round 18
// 688.445 us; speedup vs baseline: 1.1172x; 1.0025x over previous
//
#include <hip/hip_runtime.h>

#define N_NODES 100000
#define N_EDGES 1600000
#define N_GRAPHS 64
#define DIM 128
#define BN_EPS 1e-5f
#define EPAD 2000000          // sentinel-filled esrc capacity (needs 1,903,419)

#define NB_DEG 6250           // dego atomics: 6250*256 = 1.6M edges
#define NB_EMB 6250           // embed: 100k nodes * 16 thr
#define NB_SENT 977           // esrc sentinel fill, 8 per thread
#define NB_WPREP 192          // 3*128*128/256
#define NB_HIST 391           // coarse hist: 391 chunks * 4096 edges
#define NBUCK 782             // coarse buckets = dst>>7 (100000/128)
#define NG (NBUCK * NB_HIST)  // count-matrix size = 305762
#define NB_SCANG 1195         // ceil(NG/256)
#define BUCK_RESERVE 388      // cnt + 128*3 pad + 4 align slack

#define AT_STRIDE 136  // 128 + 8 pad: 2-way-only LDS bank aliasing

typedef unsigned short ushort_t;
typedef unsigned char uchar_t;
typedef unsigned int uint_t;
typedef __attribute__((ext_vector_type(8))) short bf16x8;
typedef __attribute__((ext_vector_type(4))) float f32x4;

__device__ __forceinline__ float bfl(uint_t u) {
    union { uint_t i; float f; } v; v.i = u << 16; return v.f;
}
__device__ __forceinline__ float bfh(uint_t u) {
    union { uint_t i; float f; } v; v.i = u & 0xffff0000u; return v.f;
}
__device__ __forceinline__ ushort_t f2bf(float f) {
    union { float f; uint_t i; } v; v.f = f;
    uint_t x = v.i;
    return (ushort_t)((x + 0x7fffu + ((x >> 16) & 1u)) >> 16);
}
__device__ __forceinline__ uint_t pack2(float lo, float hi) {
    return ((uint_t)f2bf(hi) << 16) | (uint_t)f2bf(lo);
}

// ---------------- zero scratch ----------------
__global__ void k_zero(int* __restrict__ p, int n) {
    int i = blockIdx.x * blockDim.x + threadIdx.x;
    if (i < n) p[i] = 0;
}

// ---------------- front mega-kernel: {dego | embed | sentinel | wprep | coarse-hist} ----------------
__global__ void k_front(const int* __restrict__ src, const int* __restrict__ dst,
                        int* __restrict__ dego,
                        const int* __restrict__ tokens, const float* __restrict__ embed,
                        ushort_t* __restrict__ bufH, ushort_t* __restrict__ bufA,
                        int* __restrict__ esrc,
                        const float* __restrict__ w1, const float* __restrict__ w2,
                        const float* __restrict__ w3, ushort_t* __restrict__ wbt,
                        int* __restrict__ G) {
    __shared__ int hh[NBUCK];
    int b = blockIdx.x;
    int t = threadIdx.x;
    if (b < NB_DEG) {
        int e = b * 256 + t;
        if (e < N_EDGES) atomicAdd(&dego[src[e]], 1);
        return;
    }
    b -= NB_DEG;
    if (b < NB_EMB) {  // raw embedding gather (ns applied in prescale)
        int gid = b * 256 + t;
        int node = gid >> 4, sub = gid & 15;
        const float* ep = embed + (size_t)tokens[node] * DIM + sub * 8;
        float4 a = *(const float4*)ep;
        float4 c = *(const float4*)(ep + 4);
        uint4 o;
        o.x = pack2(a.x, a.y); o.y = pack2(a.z, a.w);
        o.z = pack2(c.x, c.y); o.w = pack2(c.z, c.w);
        *(uint4*)(bufH + (size_t)node * DIM + sub * 8) = o;
        return;
    }
    b -= NB_EMB;
    if (b < NB_SENT) {  // esrc sentinel fill + zero bufA sentinel feature row
        int i0 = (b * 256 + t) * 8;
        int4 sv = make_int4(N_NODES, N_NODES, N_NODES, N_NODES);
        if (i0 + 8 <= EPAD) {
            *(int4*)(esrc + i0) = sv;
            *(int4*)(esrc + i0 + 4) = sv;
        } else {
            for (int i = i0; i < EPAD; ++i) esrc[i] = N_NODES;
        }
        if (b == 0 && t < 64)
            ((uint_t*)(bufA + (size_t)N_NODES * DIM))[t] = 0u;
        return;
    }
    b -= NB_SENT;
    if (b < NB_WPREP) {  // W fp32 [k][n] -> bf16 transposed [n][k]
        int i = b * 256 + t;
        int l = i >> 14;
        int idx = i & (DIM * DIM - 1);
        int n = idx >> 7, k = idx & (DIM - 1);
        const float* wsrc = (l == 0) ? w1 : (l == 1) ? w2 : w3;
        wbt[i] = f2bf(wsrc[k * DIM + n]);
        return;
    }
    b -= NB_WPREP;
    {  // coarse histogram of dst>>7: chunk b covers 4096 edges
        for (int k = t; k < NBUCK; k += 256) hh[k] = 0;
        __syncthreads();
        int e0 = b * 4096;
        int e1 = min(e0 + 4096, N_EDGES);
        for (int i = e0 + t; i < e1; i += 256) atomicAdd(&hh[dst[i] >> 7], 1);
        __syncthreads();
        for (int k = t; k < NBUCK; k += 256) G[k * NB_HIST + b] = hh[k];
    }
}

// ---------------- scan of G (bucket-major) -> exclusive Gs ----------------
__global__ void k_scanA(const int* __restrict__ G, int* __restrict__ Gs,
                        int* __restrict__ partials) {
    __shared__ int s[256];
    int t = threadIdx.x;
    int i = blockIdx.x * 256 + t;
    int v = (i < NG) ? G[i] : 0;
    s[t] = v;
    __syncthreads();
    for (int off = 1; off < 256; off <<= 1) {
        int add = (t >= off) ? s[t - off] : 0;
        __syncthreads();
        s[t] += add;
        __syncthreads();
    }
    if (i < NG) Gs[i + 1] = s[t];
    if (t == 255) partials[blockIdx.x] = s[t];
}

__global__ void k_scanB(const int* __restrict__ partials, int* __restrict__ Gs) {
    __shared__ int s[256];
    int t = threadIdx.x;
    int p = 0;
    for (int j = t; j < (int)blockIdx.x; j += 256) p += partials[j];
    s[t] = p;
    __syncthreads();
    for (int off = 128; off > 0; off >>= 1) {
        if (t < off) s[t] += s[t + off];
        __syncthreads();
    }
    int prefix = s[0];
    int i = blockIdx.x * 256 + t;
    if (i < NG) Gs[i + 1] += prefix;
    if (blockIdx.x == 0 && t == 0) Gs[0] = 0;
}

// ---------------- pass 2: coarse scatter into bucket-sorted (Csrc, Cdl) ----------------
__global__ void k_pass2(const int* __restrict__ src, const int* __restrict__ dst,
                        const int* __restrict__ Gs, int* __restrict__ Csrc,
                        uchar_t* __restrict__ Cdl) {
    __shared__ int cur[NBUCK];
    int b = blockIdx.x;  // 391 blocks
    int t = threadIdx.x;
    for (int k = t; k < NBUCK; k += 256) cur[k] = Gs[k * NB_HIST + b];
    __syncthreads();
    int e0 = b * 4096;
    int e1 = min(e0 + 4096, N_EDGES);
    for (int i = e0 + t; i < e1; i += 256) {
        int d = dst[i];
        int slot = atomicAdd(&cur[d >> 7], 1);
        Csrc[slot] = src[i];
        Cdl[slot] = (uchar_t)(d & 127);
    }
}

// ---------------- pass 3: per-bucket fine build: rowptr/pdeg/nd/ns + esrc ----------------
__global__ void k_fine(const int* __restrict__ Csrc, const uchar_t* __restrict__ Cdl,
                       const int* __restrict__ Gs, const int* __restrict__ dego,
                       int* __restrict__ esrc, int* __restrict__ rowptr,
                       int* __restrict__ pdeg, float* __restrict__ ns,
                       float* __restrict__ nd) {
    __shared__ int hcnt[128];
    __shared__ int hstart[128];
    int k = blockIdx.x;  // 782 buckets
    int t = threadIdx.x;
    int node0 = k * 128;
    int nn = min(128, N_NODES - node0);
    int S = Gs[k * NB_HIST];
    int E = Gs[(k + 1) * NB_HIST];
    if (t < 128) hcnt[t] = 0;
    __syncthreads();
    for (int i = S + t; i < E; i += 256) atomicAdd(&hcnt[Cdl[i]], 1);
    __syncthreads();
    if (t == 0) {
        int acc = 0;
        for (int n = 0; n < nn; ++n) {
            hstart[n] = acc;
            acc += (hcnt[n] + 3) & ~3;
        }
    }
    __syncthreads();
    int base = (k * BUCK_RESERVE + S + 3) & ~3;
    if (t < nn) {
        int node = node0 + t;
        rowptr[node] = base + hstart[t];
        pdeg[node] = (hcnt[t] + 3) & ~3;
        nd[node] = rsqrtf(fmaxf((float)hcnt[t], 1.0f));
        ns[node] = rsqrtf(fmaxf((float)dego[node], 1.0f));
    }
    if (k == 0 && t == 0) ns[N_NODES] = 0.f;
    __syncthreads();
    for (int i = S + t; i < E; i += 256) {
        int slot = atomicAdd(&hstart[Cdl[i]], 1);
        esrc[base + slot] = Csrc[i];
    }
}

// ---------------- prescale: x[v] = (BN? relu(fma(y,a,c)) : y) * ns[v], bf16 ----------------
template <int DOBN>
__global__ void k_prescale(const ushort_t* __restrict__ yin, const float* __restrict__ ns,
                           const float* __restrict__ bnsum, const float* __restrict__ bnsq,
                           const float* __restrict__ g, const float* __restrict__ be,
                           ushort_t* __restrict__ xout) {
    __shared__ float sa[DIM], sc[DIM];
    int t = threadIdx.x;
    if (DOBN) {
        if (t < DIM) {
            float mu = bnsum[t] * (1.0f / N_NODES);
            float var = bnsq[t] * (1.0f / N_NODES) - mu * mu;
            float rstd = rsqrtf(var + BN_EPS);
            float a = g[t] * rstd;
            sa[t] = a;
            sc[t] = be[t] - mu * a;
        }
        __syncthreads();
    }
    int gid = blockIdx.x * 256 + t;  // 6250 blocks * 256 = N*16 exactly
    int node = gid >> 4, sub = gid & 15;
    float s = ns[node];
    uint4 u = *(const uint4*)(yin + (size_t)node * DIM + sub * 8);
    float v[8] = {bfl(u.x), bfh(u.x), bfl(u.y), bfh(u.y),
                  bfl(u.z), bfh(u.z), bfl(u.w), bfh(u.w)};
    if (DOBN) {
        const float* a = sa + sub * 8;
        const float* c = sc + sub * 8;
#pragma unroll
        for (int i = 0; i < 8; ++i) v[i] = fmaxf(fmaf(v[i], a[i], c[i]), 0.f);
    }
#pragma unroll
    for (int i = 0; i < 8; ++i) v[i] *= s;
    uint4 o;
    o.x = pack2(v[0], v[1]); o.y = pack2(v[2], v[3]);
    o.z = pack2(v[4], v[5]); o.w = pack2(v[6], v[7]);
    *(uint4*)(xout + (size_t)node * DIM + sub * 8) = o;
}

// ---------------- FUSED pure-sum gather (2-node pipeline, idx prefetched one
// iteration ahead) -> LDS -> MFMA + BN stats. Barrier-free until the final
// stats reduce (A-tile and csum/csq rows are wave-private). ----------------
__global__ __launch_bounds__(256) void k_agggemm(const ushort_t* __restrict__ hs,
        const int* __restrict__ rowptr, const int* __restrict__ pdeg,
        const int* __restrict__ esrc, const float* __restrict__ nd,
        const ushort_t* __restrict__ wbt, const float* __restrict__ bias,
        ushort_t* __restrict__ y,
        float* __restrict__ bnsum, float* __restrict__ bnsq) {
    __shared__ ushort_t at[64 * AT_STRIDE];
    __shared__ float csum[4][DIM], csq[4][DIM];  // per-wave rows
    int tid = threadIdx.x;
    int wave = tid >> 6;
    int lane = tid & 63;
    // per-wave stats init (no barrier needed: rows are wave-private)
    csum[wave][lane] = 0.f;
    csum[wave][lane + 64] = 0.f;
    csq[wave][lane] = 0.f;
    csq[wave][lane + 64] = 0.f;

    int bnode = blockIdx.x * 64 + wave * 16;
    int off = lane * 2;

    // prefetch the wave's 16 row starts + padded degrees, serve via shfl
    int rpv = 0, pdv = 0;
    if (lane < 16) {
        int nnode = bnode + lane;
        if (nnode < N_NODES) { rpv = rowptr[nnode]; pdv = pdeg[nnode]; }
    }

#define LD2(s) (*(const uint_t*)(hs + (size_t)(s) * DIM + off))
#define ACC8(I0, I1, X0, Y0, X1, Y1)                                           \
    {                                                                          \
        uint_t u0 = LD2(I0.x), u1 = LD2(I0.y), u2 = LD2(I0.z), u3 = LD2(I0.w); \
        uint_t u4 = LD2(I1.x), u5 = LD2(I1.y), u6 = LD2(I1.z), u7 = LD2(I1.w); \
        X0 += bfl(u0); Y0 += bfh(u0); X1 += bfl(u1); Y1 += bfh(u1);            \
        X0 += bfl(u2); Y0 += bfh(u2); X1 += bfl(u3); Y1 += bfh(u3);            \
        X0 += bfl(u4); Y0 += bfh(u4); X1 += bfl(u5); Y1 += bfh(u5);            \
        X0 += bfl(u6); Y0 += bfh(u6); X1 += bfl(u7); Y1 += bfh(u7);            \
    }
#define ACC4(I0, X0, Y0, X1, Y1)                                               \
    {                                                                          \
        uint_t u0 = LD2(I0.x), u1 = LD2(I0.y), u2 = LD2(I0.z), u3 = LD2(I0.w); \
        X0 += bfl(u0); Y0 += bfh(u0); X1 += bfl(u1); Y1 += bfh(u1);            \
        X0 += bfl(u2); Y0 += bfh(u2); X1 += bfl(u3); Y1 += bfh(u3);            \
    }

    // ---- phase 1: gather, 2 nodes in flight, indices pipelined 1 iter ahead ----
    for (int i = 0; i < 16; i += 2) {
        int nodeA = bnode + i;
        int nodeB = bnode + i + 1;
        int eA = __shfl(rpv, i);
        int endA = eA + __shfl(pdv, i);
        int eB = __shfl(rpv, i + 1);
        int endB = eB + __shfl(pdv, i + 1);
        float xA0 = 0.f, yA0 = 0.f, xA1 = 0.f, yA1 = 0.f;
        float xB0 = 0.f, yB0 = 0.f, xB1 = 0.f, yB1 = 0.f;
        // joint main loop: 16 feature loads in flight; next iter's idx loads
        // issued under the feature-load latency (prefetch past row end is safe:
        // EPAD slack; values discarded on exit).
        if (eA + 8 <= endA && eB + 8 <= endB) {
            int4 cA0 = *(const int4*)(esrc + eA);
            int4 cA1 = *(const int4*)(esrc + eA + 4);
            int4 cB0 = *(const int4*)(esrc + eB);
            int4 cB1 = *(const int4*)(esrc + eB + 4);
            while (true) {
                int4 nA0 = *(const int4*)(esrc + eA + 8);
                int4 nA1 = *(const int4*)(esrc + eA + 12);
                int4 nB0 = *(const int4*)(esrc + eB + 8);
                int4 nB1 = *(const int4*)(esrc + eB + 12);
                ACC8(cA0, cA1, xA0, yA0, xA1, yA1);
                ACC8(cB0, cB1, xB0, yB0, xB1, yB1);
                eA += 8; eB += 8;
                if (!(eA + 8 <= endA && eB + 8 <= endB)) break;
                cA0 = nA0; cA1 = nA1; cB0 = nB0; cB1 = nB1;
            }
        }
        // drain A
        for (; eA + 8 <= endA; eA += 8) {
            int4 i0 = *(const int4*)(esrc + eA);
            int4 i1 = *(const int4*)(esrc + eA + 4);
            ACC8(i0, i1, xA0, yA0, xA1, yA1);
        }
        if (eA < endA) {  // exactly 4 (rows padded to x4)
            int4 i0 = *(const int4*)(esrc + eA);
            ACC4(i0, xA0, yA0, xA1, yA1);
        }
        // drain B
        for (; eB + 8 <= endB; eB += 8) {
            int4 i0 = *(const int4*)(esrc + eB);
            int4 i1 = *(const int4*)(esrc + eB + 4);
            ACC8(i0, i1, xB0, yB0, xB1, yB1);
        }
        if (eB < endB) {
            int4 i0 = *(const int4*)(esrc + eB);
            ACC4(i0, xB0, yB0, xB1, yB1);
        }
        // finalize both nodes
        uint_t ovA = 0u, ovB = 0u;
        if (nodeA < N_NODES) {
            float n = nd[nodeA];
            ovA = pack2((xA0 + xA1) * n, (yA0 + yA1) * n);
        }
        if (nodeB < N_NODES) {
            float n = nd[nodeB];
            ovB = pack2((xB0 + xB1) * n, (yB0 + yB1) * n);
        }
        *(uint_t*)&at[(wave * 16 + i) * AT_STRIDE + off] = ovA;
        *(uint_t*)&at[(wave * 16 + i + 1) * AT_STRIDE + off] = ovB;
    }
#undef ACC8
#undef ACC4
#undef LD2
    // NO barrier: each wave's MFMA reads only its own 16 LDS rows.

    // ---- phase 2: MFMA (D: col=lane&15, row=quad*4+reg) ----
    int m16 = lane & 15;
    int quad = lane >> 4;
    f32x4 acc[8];
#pragma unroll
    for (int nb = 0; nb < 8; ++nb) acc[nb] = (f32x4)(0.f);

    const ushort_t* ap = &at[(wave * 16 + m16) * AT_STRIDE + quad * 8];
#pragma unroll
    for (int k0b = 0; k0b < 4; ++k0b) {
        bf16x8 af = *(const bf16x8*)(ap + k0b * 32);
#pragma unroll
        for (int nb = 0; nb < 8; ++nb) {
            int ncol = nb * 16 + m16;
            bf16x8 bfg = *(const bf16x8*)(wbt + (size_t)ncol * DIM + k0b * 32 + quad * 8);
            acc[nb] = __builtin_amdgcn_mfma_f32_16x16x32_bf16(af, bfg, acc[nb], 0, 0, 0);
        }
    }

    // epilogue: bias, per-wave BN partial stats, bf16 store
#pragma unroll
    for (int nb = 0; nb < 8; ++nb) {
        int col = nb * 16 + m16;
        float bcol = bias[col];
        float ps = 0.f, pq = 0.f;
#pragma unroll
        for (int reg = 0; reg < 4; ++reg) {
            int r = bnode + quad * 4 + reg;
            if (r < N_NODES) {
                float v = acc[nb][reg] + bcol;
                ps += v; pq += v * v;
                y[(size_t)r * DIM + col] = f2bf(v);
            }
        }
        atomicAdd(&csum[wave][col], ps);
        atomicAdd(&csq[wave][col], pq);
    }
    __syncthreads();  // single barrier: cross-wave stats reduce
    if (tid < DIM) {
        float s = csum[0][tid] + csum[1][tid] + csum[2][tid] + csum[3][tid];
        float q = csq[0][tid] + csq[1][tid] + csq[2][tid] + csq[3][tid];
        atomicAdd(&bnsum[tid], s);
        atomicAdd(&bnsq[tid], q);
    }
}

// ---------------- pooling: fused layer-3 BN fold+apply + graph counts ----------------
#define POOL_NODES 128
__global__ void k_pool(const ushort_t* __restrict__ yin, const int* __restrict__ gids,
                       const float* __restrict__ bnsum, const float* __restrict__ bnsq,
                       const float* __restrict__ g, const float* __restrict__ be,
                       float* __restrict__ pool, int* __restrict__ cnt) {
    __shared__ int h[N_GRAPHS];
    int col = threadIdx.x;  // 128
    float mu = bnsum[col] * (1.0f / N_NODES);
    float var = bnsq[col] * (1.0f / N_NODES) - mu * mu;
    float rstd = rsqrtf(var + BN_EPS);
    float a = g[col] * rstd;
    float c = be[col] - mu * a;
    if (col < N_GRAPHS) h[col] = 0;
    __syncthreads();
    int base = blockIdx.x * POOL_NODES;
    int end = min(base + POOL_NODES, N_NODES);
    for (int n = base + col; n < end; n += 128) atomicAdd(&h[gids[n]], 1);
    __syncthreads();
    if (col < N_GRAPHS && h[col]) atomicAdd(&cnt[col], h[col]);
    float acc = 0.f;
    int cur = gids[base];
    for (int n = base; n < end; ++n) {
        int gg = gids[n];
        if (gg != cur) {
            atomicAdd(&pool[(size_t)cur * DIM + col], acc);
            acc = 0.f;
            cur = gg;
        }
        uint_t u = *(const uint_t*)(yin + (size_t)n * DIM + (col & ~1));
        float v = (col & 1) ? bfh(u) : bfl(u);
        acc += fmaxf(fmaf(v, a, c), 0.f);
    }
    atomicAdd(&pool[(size_t)cur * DIM + col], acc);
}

// ---------------- final FC (one block per graph) ----------------
__global__ void k_final(const float* __restrict__ pool, const int* __restrict__ cnt,
                        const float* __restrict__ fcW1, const float* __restrict__ fcb1,
                        const float* __restrict__ fcW2, const float* __restrict__ fcb2,
                        float* __restrict__ out) {
    __shared__ float hg[DIM];
    __shared__ float z[64];
    int g = blockIdx.x;
    int t = threadIdx.x;  // 128
    float cf = fmaxf((float)cnt[g], 1.0f);
    hg[t] = pool[(size_t)g * DIM + t] / cf;
    __syncthreads();
    if (t < 64) {
        float acc = fcb1[t];
        for (int k = 0; k < DIM; ++k)
            acc += hg[k] * fcW1[k * 64 + t];
        z[t] = fmaxf(acc, 0.f);
    }
    __syncthreads();
    if (t < 2) {
        float acc = fcb2[t];
        for (int k = 0; k < 64; ++k)
            acc += z[k] * fcW2[k * 2 + t];
        out[g * 2 + t] = acc;
    }
}

extern "C" void kernel_launch(void* const* d_in, const int* in_sizes, int n_in,
                              void* d_out, int out_size, void* d_ws, size_t ws_size,
                              hipStream_t stream) {
    const int* tokens = (const int*)d_in[0];
    const int* src = (const int*)d_in[1];
    const int* dst = (const int*)d_in[2];
    const int* gids = (const int*)d_in[3];
    const float* embed = (const float*)d_in[4];
    const float* W1 = (const float*)d_in[5];
    const float* b1 = (const float*)d_in[6];
    const float* g1 = (const float*)d_in[7];
    const float* be1 = (const float*)d_in[8];
    const float* W2 = (const float*)d_in[9];
    const float* b2 = (const float*)d_in[10];
    const float* g2 = (const float*)d_in[11];
    const float* be2 = (const float*)d_in[12];
    const float* W3 = (const float*)d_in[13];
    const float* b3 = (const float*)d_in[14];
    const float* g3 = (const float*)d_in[15];
    const float* be3 = (const float*)d_in[16];
    const float* fcW1 = (const float*)d_in[17];
    const float* fcb1 = (const float*)d_in[18];
    const float* fcW2 = (const float*)d_in[19];
    const float* fcb2 = (const float*)d_in[20];
    float* out = (float*)d_out;

    char* w = (char*)d_ws;
    auto alloc = [&](size_t bytes) {
        void* p = (void*)w;
        w += (bytes + 255) & ~(size_t)255;
        return p;
    };
    ushort_t* bufH = (ushort_t*)alloc((size_t)(N_NODES + 1) * DIM * 2);  // embed raw / y2
    ushort_t* bufA = (ushort_t*)alloc((size_t)(N_NODES + 1) * DIM * 2);  // prescaled gather input
    ushort_t* bufY = (ushort_t*)alloc((size_t)(N_NODES + 1) * DIM * 2);  // y1 / y3
    int* esrc = (int*)alloc((size_t)EPAD * 4);
    int* rowptr = (int*)alloc((size_t)N_NODES * 4);
    int* pdeg = (int*)alloc((size_t)N_NODES * 4);
    float* ns = (float*)alloc((size_t)(N_NODES + 1) * 4);
    float* nd = (float*)alloc((size_t)N_NODES * 4);
    ushort_t* wbt = (ushort_t*)alloc(3 * DIM * DIM * 2);
    int* G = (int*)alloc((size_t)NG * 4);
    int* Gs = (int*)alloc((size_t)(NG + 1) * 4);
    int* partials = (int*)alloc(2048 * 4);
    int* Csrc = (int*)alloc((size_t)N_EDGES * 4);
    uchar_t* Cdl = (uchar_t*)alloc((size_t)N_EDGES);
    // zeroed region (contiguous)
    char* zstart = w;
    int* dego = (int*)alloc((size_t)N_NODES * 4);
    float* bnsum = (float*)alloc(3 * DIM * 4);
    float* bnsq = (float*)alloc(3 * DIM * 4);
    float* pool = (float*)alloc((size_t)N_GRAPHS * DIM * 4);
    int* cnt = (int*)alloc((size_t)N_GRAPHS * 4);
    int zwords = (int)((size_t)(w - zstart) / 4);

    k_zero<<<(zwords + 255) / 256, 256, 0, stream>>>((int*)zstart, zwords);
    k_front<<<NB_DEG + NB_EMB + NB_SENT + NB_WPREP + NB_HIST, 256, 0, stream>>>(
        src, dst, dego, tokens, embed, bufH, bufA, esrc, W1, W2, W3, wbt, G);
    k_scanA<<<NB_SCANG, 256, 0, stream>>>(G, Gs, partials);
    k_scanB<<<NB_SCANG, 256, 0, stream>>>(partials, Gs);
    k_pass2<<<NB_HIST, 256, 0, stream>>>(src, dst, Gs, Csrc, Cdl);
    k_fine<<<NBUCK, 256, 0, stream>>>(Csrc, Cdl, Gs, dego, esrc, rowptr, pdeg, ns, nd);

    int nb_fused = (N_NODES + 63) / 64;
    int nb_ps = 6250;  // N*16/256

    // l=0: prescale bufH -> bufA; gather bufA -> y1 in bufY
    k_prescale<0><<<nb_ps, 256, 0, stream>>>(bufH, ns, nullptr, nullptr, nullptr, nullptr, bufA);
    k_agggemm<<<nb_fused, 256, 0, stream>>>(bufA, rowptr, pdeg, esrc, nd,
                                            wbt, b1, bufY, bnsum, bnsq);
    // l=1: prescale bufY (BN stats1) -> bufA; gather -> y2 in bufH
    k_prescale<1><<<nb_ps, 256, 0, stream>>>(bufY, ns, bnsum, bnsq, g1, be1, bufA);
    k_agggemm<<<nb_fused, 256, 0, stream>>>(bufA, rowptr, pdeg, esrc, nd,
                                            wbt + (size_t)DIM * DIM, b2, bufH,
                                            bnsum + DIM, bnsq + DIM);
    // l=2: prescale bufH (BN stats2) -> bufA; gather -> y3 in bufY
    k_prescale<1><<<nb_ps, 256, 0, stream>>>(bufH, ns, bnsum + DIM, bnsq + DIM, g2, be2, bufA);
    k_agggemm<<<nb_fused, 256, 0, stream>>>(bufA, rowptr, pdeg, esrc, nd,
                                            wbt + (size_t)2 * DIM * DIM, b3, bufY,
                                            bnsum + 2 * DIM, bnsq + 2 * DIM);

    k_pool<<<(N_NODES + POOL_NODES - 1) / POOL_NODES, DIM, 0, stream>>>(
        bufY, gids, bnsum + 2 * DIM, bnsq + 2 * DIM, g3, be3, pool, cnt);
    k_final<<<N_GRAPHS, DIM, 0, stream>>>(pool, cnt, fcW1, fcb1, fcW2, fcb2, out);
}

// Round 19
// 668.005 us; speedup vs baseline: 1.1514x; 1.0306x over previous
//
#include <hip/hip_runtime.h>

#define N_NODES 100000
#define N_EDGES 1600000
#define N_GRAPHS 64
#define DIM 128
#define BN_EPS 1e-5f
#define EPAD 2000000          // sentinel-filled esrc capacity (needs 1,903,419)

#define NB_EMB 6250           // embed: 100k nodes * 16 thr
#define NB_SENT 977           // esrc sentinel fill, 8 per thread
#define NB_WPREP 192          // 3*128*128/256
#define NB_HIST 391           // coarse hist: 391 chunks * 4096 edges
#define NBUCK 782             // coarse buckets = id>>7 (100000/128)
#define NG (NBUCK * NB_HIST)  // per-side count-matrix size = 305762
#define NB_SCANG2 2389        // ceil(2*NG/256)
#define BUCK_RESERVE 388      // cnt + 128*3 pad + 4 align slack

#define AT_STRIDE 136  // 128 + 8 pad: 2-way-only LDS bank aliasing

typedef unsigned short ushort_t;
typedef unsigned char uchar_t;
typedef unsigned int uint_t;
typedef __attribute__((ext_vector_type(8))) short bf16x8;
typedef __attribute__((ext_vector_type(4))) float f32x4;

__device__ __forceinline__ float bfl(uint_t u) {
    union { uint_t i; float f; } v; v.i = u << 16; return v.f;
}
__device__ __forceinline__ float bfh(uint_t u) {
    union { uint_t i; float f; } v; v.i = u & 0xffff0000u; return v.f;
}
__device__ __forceinline__ ushort_t f2bf(float f) {
    union { float f; uint_t i; } v; v.f = f;
    uint_t x = v.i;
    return (ushort_t)((x + 0x7fffu + ((x >> 16) & 1u)) >> 16);
}
__device__ __forceinline__ uint_t pack2(float lo, float hi) {
    return ((uint_t)f2bf(hi) << 16) | (uint_t)f2bf(lo);
}

// ---------------- zero scratch ----------------
__global__ void k_zero(int* __restrict__ p, int n) {
    int i = blockIdx.x * blockDim.x + threadIdx.x;
    if (i < n) p[i] = 0;
}

// ---------------- front mega-kernel: {embed | sentinel | wprep | dual coarse-hist} ----------------
// Atomic-free: both dst- and src-side coarse histograms use LDS.
__global__ void k_front(const int* __restrict__ src, const int* __restrict__ dst,
                        const int* __restrict__ tokens, const float* __restrict__ embed,
                        ushort_t* __restrict__ bufH, ushort_t* __restrict__ bufA,
                        int* __restrict__ esrc,
                        const float* __restrict__ w1, const float* __restrict__ w2,
                        const float* __restrict__ w3, ushort_t* __restrict__ wbt,
                        int* __restrict__ GG) {
    __shared__ int hh[NBUCK];
    __shared__ int hh2[NBUCK];
    int b = blockIdx.x;
    int t = threadIdx.x;
    if (b < NB_EMB) {  // raw embedding gather (ns applied in prescale)
        int gid = b * 256 + t;
        int node = gid >> 4, sub = gid & 15;
        const float* ep = embed + (size_t)tokens[node] * DIM + sub * 8;
        float4 a = *(const float4*)ep;
        float4 c = *(const float4*)(ep + 4);
        uint4 o;
        o.x = pack2(a.x, a.y); o.y = pack2(a.z, a.w);
        o.z = pack2(c.x, c.y); o.w = pack2(c.z, c.w);
        *(uint4*)(bufH + (size_t)node * DIM + sub * 8) = o;
        return;
    }
    b -= NB_EMB;
    if (b < NB_SENT) {  // esrc sentinel fill + zero bufA sentinel feature row
        int i0 = (b * 256 + t) * 8;
        int4 sv = make_int4(N_NODES, N_NODES, N_NODES, N_NODES);
        if (i0 + 8 <= EPAD) {
            *(int4*)(esrc + i0) = sv;
            *(int4*)(esrc + i0 + 4) = sv;
        } else {
            for (int i = i0; i < EPAD; ++i) esrc[i] = N_NODES;
        }
        if (b == 0 && t < 64)
            ((uint_t*)(bufA + (size_t)N_NODES * DIM))[t] = 0u;
        return;
    }
    b -= NB_SENT;
    if (b < NB_WPREP) {  // W fp32 [k][n] -> bf16 transposed [n][k]
        int i = b * 256 + t;
        int l = i >> 14;
        int idx = i & (DIM * DIM - 1);
        int n = idx >> 7, k = idx & (DIM - 1);
        const float* wsrc = (l == 0) ? w1 : (l == 1) ? w2 : w3;
        wbt[i] = f2bf(wsrc[k * DIM + n]);
        return;
    }
    b -= NB_WPREP;
    {  // dual coarse histogram (dst>>7 and src>>7): chunk b covers 4096 edges
        for (int k = t; k < NBUCK; k += 256) { hh[k] = 0; hh2[k] = 0; }
        __syncthreads();
        int e0 = b * 4096;
        int e1 = min(e0 + 4096, N_EDGES);
        for (int i = e0 + t; i < e1; i += 256) {
            atomicAdd(&hh[dst[i] >> 7], 1);
            atomicAdd(&hh2[src[i] >> 7], 1);
        }
        __syncthreads();
        for (int k = t; k < NBUCK; k += 256) {
            GG[k * NB_HIST + b] = hh[k];
            GG[NG + k * NB_HIST + b] = hh2[k];
        }
    }
}

// ---------------- scan of GG (both sides concatenated) -> exclusive Gs ----------------
__global__ void k_scanA(const int* __restrict__ GG, int* __restrict__ Gs,
                        int* __restrict__ partials) {
    __shared__ int s[256];
    int t = threadIdx.x;
    int i = blockIdx.x * 256 + t;
    int v = (i < 2 * NG) ? GG[i] : 0;
    s[t] = v;
    __syncthreads();
    for (int off = 1; off < 256; off <<= 1) {
        int add = (t >= off) ? s[t - off] : 0;
        __syncthreads();
        s[t] += add;
        __syncthreads();
    }
    if (i < 2 * NG) Gs[i + 1] = s[t];
    if (t == 255) partials[blockIdx.x] = s[t];
}

__global__ void k_scanB(const int* __restrict__ partials, int* __restrict__ Gs) {
    __shared__ int s[256];
    int t = threadIdx.x;
    int p = 0;
    for (int j = t; j < (int)blockIdx.x; j += 256) p += partials[j];
    s[t] = p;
    __syncthreads();
    for (int off = 128; off > 0; off >>= 1) {
        if (t < off) s[t] += s[t + off];
        __syncthreads();
    }
    int prefix = s[0];
    int i = blockIdx.x * 256 + t;
    if (i < 2 * NG) Gs[i + 1] += prefix;
    if (blockIdx.x == 0 && t == 0) Gs[0] = 0;
}

// ---------------- pass 2: coarse scatter, dst side (Csrc,Cdl) + src side (Cls) ----------------
__global__ void k_pass2(const int* __restrict__ src, const int* __restrict__ dst,
                        const int* __restrict__ Gs, int* __restrict__ Csrc,
                        uchar_t* __restrict__ Cdl, uchar_t* __restrict__ Cls) {
    __shared__ int cur[NBUCK];
    __shared__ int cur2[NBUCK];
    int b = blockIdx.x;  // 391 blocks
    int t = threadIdx.x;
    for (int k = t; k < NBUCK; k += 256) {
        cur[k] = Gs[k * NB_HIST + b];
        cur2[k] = Gs[NG + k * NB_HIST + b] - N_EDGES;
    }
    __syncthreads();
    int e0 = b * 4096;
    int e1 = min(e0 + 4096, N_EDGES);
    for (int i = e0 + t; i < e1; i += 256) {
        int d = dst[i];
        int s = src[i];
        int slot = atomicAdd(&cur[d >> 7], 1);
        Csrc[slot] = s;
        Cdl[slot] = (uchar_t)(d & 127);
        int slot2 = atomicAdd(&cur2[s >> 7], 1);
        Cls[slot2] = (uchar_t)(s & 127);
    }
}

// ---------------- pass 3, dual partition:
// blocks [0,NBUCK): dst-side fine build (rowptr/pdeg/nd + esrc)
// blocks [NBUCK,2*NBUCK): src-side fine histogram -> ns ----------------
__global__ void k_fine(const int* __restrict__ Csrc, const uchar_t* __restrict__ Cdl,
                       const uchar_t* __restrict__ Cls, const int* __restrict__ Gs,
                       int* __restrict__ esrc, int* __restrict__ rowptr,
                       int* __restrict__ pdeg, float* __restrict__ ns,
                       float* __restrict__ nd) {
    __shared__ int hcnt[128];
    __shared__ int hstart[128];
    int b = blockIdx.x;
    int t = threadIdx.x;
    if (b < NBUCK) {  // dst side
        int k = b;
        int node0 = k * 128;
        int nn = min(128, N_NODES - node0);
        int S = Gs[k * NB_HIST];
        int E = Gs[(k + 1) * NB_HIST];
        if (t < 128) hcnt[t] = 0;
        __syncthreads();
        for (int i = S + t; i < E; i += 256) atomicAdd(&hcnt[Cdl[i]], 1);
        __syncthreads();
        if (t == 0) {
            int acc = 0;
            for (int n = 0; n < nn; ++n) {
                hstart[n] = acc;
                acc += (hcnt[n] + 3) & ~3;
            }
        }
        __syncthreads();
        int base = (k * BUCK_RESERVE + S + 3) & ~3;
        if (t < nn) {
            int node = node0 + t;
            rowptr[node] = base + hstart[t];
            pdeg[node] = (hcnt[t] + 3) & ~3;
            nd[node] = rsqrtf(fmaxf((float)hcnt[t], 1.0f));
        }
        __syncthreads();
        for (int i = S + t; i < E; i += 256) {
            int slot = atomicAdd(&hstart[Cdl[i]], 1);
            esrc[base + slot] = Csrc[i];
        }
    } else {  // src side -> ns
        int k = b - NBUCK;
        int node0 = k * 128;
        int nn = min(128, N_NODES - node0);
        int S = Gs[NG + k * NB_HIST] - N_EDGES;
        int E = Gs[NG + (k + 1) * NB_HIST] - N_EDGES;
        if (t < 128) hcnt[t] = 0;
        __syncthreads();
        for (int i = S + t; i < E; i += 256) atomicAdd(&hcnt[Cls[i]], 1);
        __syncthreads();
        if (t < nn)
            ns[node0 + t] = rsqrtf(fmaxf((float)hcnt[t], 1.0f));
        if (k == 0 && t == 0) ns[N_NODES] = 0.f;  // kills sentinel contributions
    }
}

// ---------------- prescale: x[v] = (BN? relu(fma(y,a,c)) : y) * ns[v], bf16 ----------------
template <int DOBN>
__global__ void k_prescale(const ushort_t* __restrict__ yin, const float* __restrict__ ns,
                           const float* __restrict__ bnsum, const float* __restrict__ bnsq,
                           const float* __restrict__ g, const float* __restrict__ be,
                           ushort_t* __restrict__ xout) {
    __shared__ float sa[DIM], sc[DIM];
    int t = threadIdx.x;
    if (DOBN) {
        if (t < DIM) {
            float mu = bnsum[t] * (1.0f / N_NODES);
            float var = bnsq[t] * (1.0f / N_NODES) - mu * mu;
            float rstd = rsqrtf(var + BN_EPS);
            float a = g[t] * rstd;
            sa[t] = a;
            sc[t] = be[t] - mu * a;
        }
        __syncthreads();
    }
    int gid = blockIdx.x * 256 + t;  // 6250 blocks * 256 = N*16 exactly
    int node = gid >> 4, sub = gid & 15;
    float s = ns[node];
    uint4 u = *(const uint4*)(yin + (size_t)node * DIM + sub * 8);
    float v[8] = {bfl(u.x), bfh(u.x), bfl(u.y), bfh(u.y),
                  bfl(u.z), bfh(u.z), bfl(u.w), bfh(u.w)};
    if (DOBN) {
        const float* a = sa + sub * 8;
        const float* c = sc + sub * 8;
#pragma unroll
        for (int i = 0; i < 8; ++i) v[i] = fmaxf(fmaf(v[i], a[i], c[i]), 0.f);
    }
#pragma unroll
    for (int i = 0; i < 8; ++i) v[i] *= s;
    uint4 o;
    o.x = pack2(v[0], v[1]); o.y = pack2(v[2], v[3]);
    o.z = pack2(v[4], v[5]); o.w = pack2(v[6], v[7]);
    *(uint4*)(xout + (size_t)node * DIM + sub * 8) = o;
}

// ---------------- FUSED pure-sum gather (2-node pipeline, idx prefetched one
// iteration ahead) -> LDS -> MFMA + BN stats. Barrier-free until the final
// stats reduce (A-tile and csum/csq rows are wave-private). ----------------
__global__ __launch_bounds__(256) void k_agggemm(const ushort_t* __restrict__ hs,
        const int* __restrict__ rowptr, const int* __restrict__ pdeg,
        const int* __restrict__ esrc, const float* __restrict__ nd,
        const ushort_t* __restrict__ wbt, const float* __restrict__ bias,
        ushort_t* __restrict__ y,
        float* __restrict__ bnsum, float* __restrict__ bnsq) {
    __shared__ ushort_t at[64 * AT_STRIDE];
    __shared__ float csum[4][DIM], csq[4][DIM];  // per-wave rows
    int tid = threadIdx.x;
    int wave = tid >> 6;
    int lane = tid & 63;
    // per-wave stats init (no barrier needed: rows are wave-private)
    csum[wave][lane] = 0.f;
    csum[wave][lane + 64] = 0.f;
    csq[wave][lane] = 0.f;
    csq[wave][lane + 64] = 0.f;

    int bnode = blockIdx.x * 64 + wave * 16;
    int off = lane * 2;

    // prefetch the wave's 16 row starts + padded degrees, serve via shfl
    int rpv = 0, pdv = 0;
    if (lane < 16) {
        int nnode = bnode + lane;
        if (nnode < N_NODES) { rpv = rowptr[nnode]; pdv = pdeg[nnode]; }
    }

#define LD2(s) (*(const uint_t*)(hs + (size_t)(s) * DIM + off))
#define ACC8(I0, I1, X0, Y0, X1, Y1)                                           \
    {                                                                          \
        uint_t u0 = LD2(I0.x), u1 = LD2(I0.y), u2 = LD2(I0.z), u3 = LD2(I0.w); \
        uint_t u4 = LD2(I1.x), u5 = LD2(I1.y), u6 = LD2(I1.z), u7 = LD2(I1.w); \
        X0 += bfl(u0); Y0 += bfh(u0); X1 += bfl(u1); Y1 += bfh(u1);            \
        X0 += bfl(u2); Y0 += bfh(u2); X1 += bfl(u3); Y1 += bfh(u3);            \
        X0 += bfl(u4); Y0 += bfh(u4); X1 += bfl(u5); Y1 += bfh(u5);            \
        X0 += bfl(u6); Y0 += bfh(u6); X1 += bfl(u7); Y1 += bfh(u7);            \
    }
#define ACC4(I0, X0, Y0, X1, Y1)                                               \
    {                                                                          \
        uint_t u0 = LD2(I0.x), u1 = LD2(I0.y), u2 = LD2(I0.z), u3 = LD2(I0.w); \
        X0 += bfl(u0); Y0 += bfh(u0); X1 += bfl(u1); Y1 += bfh(u1);            \
        X0 += bfl(u2); Y0 += bfh(u2); X1 += bfl(u3); Y1 += bfh(u3);            \
    }

    // ---- phase 1: gather, 2 nodes in flight, indices pipelined 1 iter ahead ----
    for (int i = 0; i < 16; i += 2) {
        int nodeA = bnode + i;
        int nodeB = bnode + i + 1;
        int eA = __shfl(rpv, i);
        int endA = eA + __shfl(pdv, i);
        int eB = __shfl(rpv, i + 1);
        int endB = eB + __shfl(pdv, i + 1);
        float xA0 = 0.f, yA0 = 0.f, xA1 = 0.f, yA1 = 0.f;
        float xB0 = 0.f, yB0 = 0.f, xB1 = 0.f, yB1 = 0.f;
        // joint main loop: 16 feature loads in flight; next iter's idx loads
        // issued under the feature-load latency (prefetch past row end is safe:
        // EPAD slack; values discarded on exit).
        if (eA + 8 <= endA && eB + 8 <= endB) {
            int4 cA0 = *(const int4*)(esrc + eA);
            int4 cA1 = *(const int4*)(esrc + eA + 4);
            int4 cB0 = *(const int4*)(esrc + eB);
            int4 cB1 = *(const int4*)(esrc + eB + 4);
            while (true) {
                int4 nA0 = *(const int4*)(esrc + eA + 8);
                int4 nA1 = *(const int4*)(esrc + eA + 12);
                int4 nB0 = *(const int4*)(esrc + eB + 8);
                int4 nB1 = *(const int4*)(esrc + eB + 12);
                ACC8(cA0, cA1, xA0, yA0, xA1, yA1);
                ACC8(cB0, cB1, xB0, yB0, xB1, yB1);
                eA += 8; eB += 8;
                if (!(eA + 8 <= endA && eB + 8 <= endB)) break;
                cA0 = nA0; cA1 = nA1; cB0 = nB0; cB1 = nB1;
            }
        }
        // drain A
        for (; eA + 8 <= endA; eA += 8) {
            int4 i0 = *(const int4*)(esrc + eA);
            int4 i1 = *(const int4*)(esrc + eA + 4);
            ACC8(i0, i1, xA0, yA0, xA1, yA1);
        }
        if (eA < endA) {  // exactly 4 (rows padded to x4)
            int4 i0 = *(const int4*)(esrc + eA);
            ACC4(i0, xA0, yA0, xA1, yA1);
        }
        // drain B
        for (; eB + 8 <= endB; eB += 8) {
            int4 i0 = *(const int4*)(esrc + eB);
            int4 i1 = *(const int4*)(esrc + eB + 4);
            ACC8(i0, i1, xB0, yB0, xB1, yB1);
        }
        if (eB < endB) {
            int4 i0 = *(const int4*)(esrc + eB);
            ACC4(i0, xB0, yB0, xB1, yB1);
        }
        // finalize both nodes
        uint_t ovA = 0u, ovB = 0u;
        if (nodeA < N_NODES) {
            float n = nd[nodeA];
            ovA = pack2((xA0 + xA1) * n, (yA0 + yA1) * n);
        }
        if (nodeB < N_NODES) {
            float n = nd[nodeB];
            ovB = pack2((xB0 + xB1) * n, (yB0 + yB1) * n);
        }
        *(uint_t*)&at[(wave * 16 + i) * AT_STRIDE + off] = ovA;
        *(uint_t*)&at[(wave * 16 + i + 1) * AT_STRIDE + off] = ovB;
    }
#undef ACC8
#undef ACC4
#undef LD2
    // NO barrier: each wave's MFMA reads only its own 16 LDS rows.

    // ---- phase 2: MFMA (D: col=lane&15, row=quad*4+reg) ----
    int m16 = lane & 15;
    int quad = lane >> 4;
    f32x4 acc[8];
#pragma unroll
    for (int nb = 0; nb < 8; ++nb) acc[nb] = (f32x4)(0.f);

    const ushort_t* ap = &at[(wave * 16 + m16) * AT_STRIDE + quad * 8];
#pragma unroll
    for (int k0b = 0; k0b < 4; ++k0b) {
        bf16x8 af = *(const bf16x8*)(ap + k0b * 32);
#pragma unroll
        for (int nb = 0; nb < 8; ++nb) {
            int ncol = nb * 16 + m16;
            bf16x8 bfg = *(const bf16x8*)(wbt + (size_t)ncol * DIM + k0b * 32 + quad * 8);
            acc[nb] = __builtin_amdgcn_mfma_f32_16x16x32_bf16(af, bfg, acc[nb], 0, 0, 0);
        }
    }

    // epilogue: bias, per-wave BN partial stats, bf16 store
#pragma unroll
    for (int nb = 0; nb < 8; ++nb) {
        int col = nb * 16 + m16;
        float bcol = bias[col];
        float ps = 0.f, pq = 0.f;
#pragma unroll
        for (int reg = 0; reg < 4; ++reg) {
            int r = bnode + quad * 4 + reg;
            if (r < N_NODES) {
                float v = acc[nb][reg] + bcol;
                ps += v; pq += v * v;
                y[(size_t)r * DIM + col] = f2bf(v);
            }
        }
        atomicAdd(&csum[wave][col], ps);
        atomicAdd(&csq[wave][col], pq);
    }
    __syncthreads();  // single barrier: cross-wave stats reduce
    if (tid < DIM) {
        float s = csum[0][tid] + csum[1][tid] + csum[2][tid] + csum[3][tid];
        float q = csq[0][tid] + csq[1][tid] + csq[2][tid] + csq[3][tid];
        atomicAdd(&bnsum[tid], s);
        atomicAdd(&bnsq[tid], q);
    }
}

// ---------------- pooling: fused layer-3 BN fold+apply + graph counts ----------------
#define POOL_NODES 128
__global__ void k_pool(const ushort_t* __restrict__ yin, const int* __restrict__ gids,
                       const float* __restrict__ bnsum, const float* __restrict__ bnsq,
                       const float* __restrict__ g, const float* __restrict__ be,
                       float* __restrict__ pool, int* __restrict__ cnt) {
    __shared__ int h[N_GRAPHS];
    int col = threadIdx.x;  // 128
    float mu = bnsum[col] * (1.0f / N_NODES);
    float var = bnsq[col] * (1.0f / N_NODES) - mu * mu;
    float rstd = rsqrtf(var + BN_EPS);
    float a = g[col] * rstd;
    float c = be[col] - mu * a;
    if (col < N_GRAPHS) h[col] = 0;
    __syncthreads();
    int base = blockIdx.x * POOL_NODES;
    int end = min(base + POOL_NODES, N_NODES);
    for (int n = base + col; n < end; n += 128) atomicAdd(&h[gids[n]], 1);
    __syncthreads();
    if (col < N_GRAPHS && h[col]) atomicAdd(&cnt[col], h[col]);
    float acc = 0.f;
    int cur = gids[base];
    for (int n = base; n < end; ++n) {
        int gg = gids[n];
        if (gg != cur) {
            atomicAdd(&pool[(size_t)cur * DIM + col], acc);
            acc = 0.f;
            cur = gg;
        }
        uint_t u = *(const uint_t*)(yin + (size_t)n * DIM + (col & ~1));
        float v = (col & 1) ? bfh(u) : bfl(u);
        acc += fmaxf(fmaf(v, a, c), 0.f);
    }
    atomicAdd(&pool[(size_t)cur * DIM + col], acc);
}

// ---------------- final FC (one block per graph) ----------------
__global__ void k_final(const float* __restrict__ pool, const int* __restrict__ cnt,
                        const float* __restrict__ fcW1, const float* __restrict__ fcb1,
                        const float* __restrict__ fcW2, const float* __restrict__ fcb2,
                        float* __restrict__ out) {
    __shared__ float hg[DIM];
    __shared__ float z[64];
    int g = blockIdx.x;
    int t = threadIdx.x;  // 128
    float cf = fmaxf((float)cnt[g], 1.0f);
    hg[t] = pool[(size_t)g * DIM + t] / cf;
    __syncthreads();
    if (t < 64) {
        float acc = fcb1[t];
        for (int k = 0; k < DIM; ++k)
            acc += hg[k] * fcW1[k * 64 + t];
        z[t] = fmaxf(acc, 0.f);
    }
    __syncthreads();
    if (t < 2) {
        float acc = fcb2[t];
        for (int k = 0; k < 64; ++k)
            acc += z[k] * fcW2[k * 2 + t];
        out[g * 2 + t] = acc;
    }
}

extern "C" void kernel_launch(void* const* d_in, const int* in_sizes, int n_in,
                              void* d_out, int out_size, void* d_ws, size_t ws_size,
                              hipStream_t stream) {
    const int* tokens = (const int*)d_in[0];
    const int* src = (const int*)d_in[1];
    const int* dst = (const int*)d_in[2];
    const int* gids = (const int*)d_in[3];
    const float* embed = (const float*)d_in[4];
    const float* W1 = (const float*)d_in[5];
    const float* b1 = (const float*)d_in[6];
    const float* g1 = (const float*)d_in[7];
    const float* be1 = (const float*)d_in[8];
    const float* W2 = (const float*)d_in[9];
    const float* b2 = (const float*)d_in[10];
    const float* g2 = (const float*)d_in[11];
    const float* be2 = (const float*)d_in[12];
    const float* W3 = (const float*)d_in[13];
    const float* b3 = (const float*)d_in[14];
    const float* g3 = (const float*)d_in[15];
    const float* be3 = (const float*)d_in[16];
    const float* fcW1 = (const float*)d_in[17];
    const float* fcb1 = (const float*)d_in[18];
    const float* fcW2 = (const float*)d_in[19];
    const float* fcb2 = (const float*)d_in[20];
    float* out = (float*)d_out;

    char* w = (char*)d_ws;
    auto alloc = [&](size_t bytes) {
        void* p = (void*)w;
        w += (bytes + 255) & ~(size_t)255;
        return p;
    };
    ushort_t* bufH = (ushort_t*)alloc((size_t)(N_NODES + 1) * DIM * 2);  // embed raw / y2
    ushort_t* bufA = (ushort_t*)alloc((size_t)(N_NODES + 1) * DIM * 2);  // prescaled gather input
    ushort_t* bufY = (ushort_t*)alloc((size_t)(N_NODES + 1) * DIM * 2);  // y1 / y3
    int* esrc = (int*)alloc((size_t)EPAD * 4);
    int* rowptr = (int*)alloc((size_t)N_NODES * 4);
    int* pdeg = (int*)alloc((size_t)N_NODES * 4);
    float* ns = (float*)alloc((size_t)(N_NODES + 1) * 4);
    float* nd = (float*)alloc((size_t)N_NODES * 4);
    ushort_t* wbt = (ushort_t*)alloc(3 * DIM * DIM * 2);
    int* GG = (int*)alloc((size_t)(2 * NG) * 4);
    int* Gs = (int*)alloc((size_t)(2 * NG + 1) * 4);
    int* partials = (int*)alloc(4096 * 4);
    int* Csrc = (int*)alloc((size_t)N_EDGES * 4);
    uchar_t* Cdl = (uchar_t*)alloc((size_t)N_EDGES);
    uchar_t* Cls = (uchar_t*)alloc((size_t)N_EDGES);
    // zeroed region (contiguous)
    char* zstart = w;
    float* bnsum = (float*)alloc(3 * DIM * 4);
    float* bnsq = (float*)alloc(3 * DIM * 4);
    float* pool = (float*)alloc((size_t)N_GRAPHS * DIM * 4);
    int* cnt = (int*)alloc((size_t)N_GRAPHS * 4);
    int zwords = (int)((size_t)(w - zstart) / 4);

    k_zero<<<(zwords + 255) / 256, 256, 0, stream>>>((int*)zstart, zwords);
    k_front<<<NB_EMB + NB_SENT + NB_WPREP + NB_HIST, 256, 0, stream>>>(
        src, dst, tokens, embed, bufH, bufA, esrc, W1, W2, W3, wbt, GG);
    k_scanA<<<NB_SCANG2, 256, 0, stream>>>(GG, Gs, partials);
    k_scanB<<<NB_SCANG2, 256, 0, stream>>>(partials, Gs);
    k_pass2<<<NB_HIST, 256, 0, stream>>>(src, dst, Gs, Csrc, Cdl, Cls);
    k_fine<<<2 * NBUCK, 256, 0, stream>>>(Csrc, Cdl, Cls, Gs, esrc, rowptr, pdeg, ns, nd);

    int nb_fused = (N_NODES + 63) / 64;
    int nb_ps = 6250;  // N*16/256

    // l=0: prescale bufH -> bufA; gather bufA -> y1 in bufY
    k_prescale<0><<<nb_ps, 256, 0, stream>>>(bufH, ns, nullptr, nullptr, nullptr, nullptr, bufA);
    k_agggemm<<<nb_fused, 256, 0, stream>>>(bufA, rowptr, pdeg, esrc, nd,
                                            wbt, b1, bufY, bnsum, bnsq);
    // l=1: prescale bufY (BN stats1) -> bufA; gather -> y2 in bufH
    k_prescale<1><<<nb_ps, 256, 0, stream>>>(bufY, ns, bnsum, bnsq, g1, be1, bufA);
    k_agggemm<<<nb_fused, 256, 0, stream>>>(bufA, rowptr, pdeg, esrc, nd,
                                            wbt + (size_t)DIM * DIM, b2, bufH,
                                            bnsum + DIM, bnsq + DIM);
    // l=2: prescale bufH (BN stats2) -> bufA; gather -> y3 in bufY
    k_prescale<1><<<nb_ps, 256, 0, stream>>>(bufH, ns, bnsum + DIM, bnsq + DIM, g2, be2, bufA);
    k_agggemm<<<nb_fused, 256, 0, stream>>>(bufA, rowptr, pdeg, esrc, nd,
                                            wbt + (size_t)2 * DIM * DIM, b3, bufY,
                                            bnsum + 2 * DIM, bnsq + 2 * DIM);

    k_pool<<<(N_NODES + POOL_NODES - 1) / POOL_NODES, DIM, 0, stream>>>(
        bufY, gids, bnsum + 2 * DIM, bnsq + 2 * DIM, g3, be3, pool, cnt);
    k_final<<<N_GRAPHS, DIM, 0, stream>>>(pool, cnt, fcW1, fcb1, fcW2, fcb2, out);
}